// Round 20
// baseline (215.126 us; speedup 1.0000x reference)
//
#include <hip/hip_runtime.h>
#include <math.h>

#define TB 2
#define TT 2048
#define TC 1024
#define TH 16
#define THD 64
#define TM (TB*TT)   // 4096 tokens
#define NQT 32       // TT/64 kv tiles

typedef __bf16 bf16x8 __attribute__((ext_vector_type(8)));
typedef float f32x4 __attribute__((ext_vector_type(4)));
typedef unsigned short u16x8 __attribute__((ext_vector_type(8)));
typedef unsigned short u16x4 __attribute__((ext_vector_type(4)));

__device__ __forceinline__ unsigned short f2bf(float f){
    unsigned int u = __builtin_bit_cast(unsigned int, f);
    u = (u + 0x7FFFu + ((u >> 16) & 1u)) >> 16;
    return (unsigned short)u;
}
__device__ __forceinline__ float bf2f(unsigned short h){
    unsigned int u = ((unsigned int)h) << 16;
    return __builtin_bit_cast(float, u);
}
__device__ __forceinline__ bf16x8 ldbf8(const unsigned short* p){
    return __builtin_bit_cast(bf16x8, *(const u16x8*)p);
}
__device__ __forceinline__ void gl_lds16(const void* g, void* l){
    __builtin_amdgcn_global_load_lds(
        (const __attribute__((address_space(1))) unsigned int*)g,
        (__attribute__((address_space(3))) unsigned int*)l,
        16, 0, 0);
}
__device__ __forceinline__ float gelu_tanh(float v){
    float u = 2.0f * 0.7978845608028654f * (v + 0.044715f * v * v * v);
    u = fminf(fmaxf(u, -30.f), 30.f);
    float e = __expf(u);
    return 0.5f * v * (1.f + (e - 1.f) / (e + 1.f));
}

// ---------------- prep: 4 weight convert+transposes AND ln1 in ONE kernel
__global__ __launch_bounds__(256)
void prep_all(const float* __restrict__ w_attn, const float* __restrict__ w_proj,
              const float* __restrict__ w_fc,   const float* __restrict__ w_fc2,
              unsigned short* __restrict__ wattnT, unsigned short* __restrict__ wprojT,
              unsigned short* __restrict__ wfcT,   unsigned short* __restrict__ wfc2T,
              const float* __restrict__ x, const float* __restrict__ ln1_g,
              const float* __restrict__ ln1_b, unsigned short* __restrict__ xn1){
    const int bid = blockIdx.x;
    const int t = threadIdx.x;
    if (bid >= 12288){
        const int row = bid - 12288;
        const float4* xr = (const float4*)(x + (size_t)row * TC);
        float4 v = xr[t];
        float s  = v.x + v.y + v.z + v.w;
        float s2 = v.x*v.x + v.y*v.y + v.z*v.z + v.w*v.w;
        #pragma unroll
        for (int off = 32; off; off >>= 1){
            s  += __shfl_down(s,  off);
            s2 += __shfl_down(s2, off);
        }
        __shared__ float red[8];
        int l = t & 63, wv = t >> 6;
        if (l == 0){ red[wv] = s; red[4 + wv] = s2; }
        __syncthreads();
        float S  = red[0] + red[1] + red[2] + red[3];
        float S2 = red[4] + red[5] + red[6] + red[7];
        float mu = S * (1.f / TC);
        float var = S2 * (1.f / TC) - mu * mu;
        float rs = rsqrtf(var + 1e-5f);
        int c = t * 4;
        float4 gg = *(const float4*)(ln1_g + c);
        float4 bb = *(const float4*)(ln1_b + c);
        u16x4 o;
        o[0] = f2bf((v.x - mu) * rs * gg.x + bb.x);
        o[1] = f2bf((v.y - mu) * rs * gg.y + bb.y);
        o[2] = f2bf((v.z - mu) * rs * gg.z + bb.z);
        o[3] = f2bf((v.w - mu) * rs * gg.w + bb.w);
        *(u16x4*)(xn1 + (size_t)row * TC + c) = o;
        return;
    }
    __shared__ float tile[32][33];
    const float* in; unsigned short* out; int K, N, bx, by;
    if (bid < 3072)      { in=w_attn; out=wattnT; K=1024; N=3072; bx=bid%96;  by=bid/96; }
    else if (bid < 4096) { int lo=bid-3072; in=w_proj; out=wprojT; K=1024; N=1024; bx=lo%32;  by=lo/32; }
    else if (bid < 8192) { int lo=bid-4096; in=w_fc;   out=wfcT;   K=1024; N=4096; bx=lo%128; by=lo/128; }
    else                 { int lo=bid-8192; in=w_fc2;  out=wfc2T;  K=4096; N=1024; bx=lo%32;  by=lo/32; }
    int tx = t & 31, ty = t >> 5;
    int n0 = bx * 32, k0 = by * 32;
    #pragma unroll
    for (int i = 0; i < 4; i++)
        tile[ty + 8*i][tx] = in[(size_t)(k0 + ty + 8*i) * N + n0 + tx];
    __syncthreads();
    #pragma unroll
    for (int i = 0; i < 4; i++)
        out[(size_t)(n0 + ty + 8*i) * K + k0 + tx] = f2bf(tile[tx][ty + 8*i]);
}

// ---------------- layernorm (ln2): x f32 [.][1024] -> y bf16
__global__ __launch_bounds__(256)
void ln_kernel(const float* __restrict__ x, const float* __restrict__ g,
               const float* __restrict__ be, unsigned short* __restrict__ y){
    const int row = blockIdx.x, t = threadIdx.x;
    const float4* xr = (const float4*)(x + (size_t)row * TC);
    float4 v = xr[t];
    float s  = v.x + v.y + v.z + v.w;
    float s2 = v.x*v.x + v.y*v.y + v.z*v.z + v.w*v.w;
    #pragma unroll
    for (int off = 32; off; off >>= 1){
        s  += __shfl_down(s,  off);
        s2 += __shfl_down(s2, off);
    }
    __shared__ float red[8];
    int l = t & 63, wv = t >> 6;
    if (l == 0){ red[wv] = s; red[4 + wv] = s2; }
    __syncthreads();
    float S  = red[0] + red[1] + red[2] + red[3];
    float S2 = red[4] + red[5] + red[6] + red[7];
    float mu = S * (1.f / TC);
    float var = S2 * (1.f / TC) - mu * mu;
    float rs = rsqrtf(var + 1e-5f);
    int c = t * 4;
    float4 gg = *(const float4*)(g + c);
    float4 bb = *(const float4*)(be + c);
    u16x4 o;
    o[0] = f2bf((v.x - mu) * rs * gg.x + bb.x);
    o[1] = f2bf((v.y - mu) * rs * gg.y + bb.y);
    o[2] = f2bf((v.z - mu) * rs * gg.z + bb.z);
    o[3] = f2bf((v.w - mu) * rs * gg.w + bb.w);
    *(u16x4*)(y + (size_t)row * TC + c) = o;
}

// ---------------- 128x128 GEMM (m97 structure) + XCD swizzle
// EPI 0: +bias->bf16 ; 1: +bias+resid->f32 ; 2: +bias,gelu->bf16
template<int EPI>
__global__ __launch_bounds__(256, 2)
void gemm_bt(const unsigned short* __restrict__ A,
             const unsigned short* __restrict__ Bt,
             const float* __restrict__ bias,
             const float* __restrict__ resid,
             void* __restrict__ outv,
             int M, int N, int K){
    __shared__ unsigned short lA[128 * 32];
    __shared__ unsigned short lB[128 * 32];
    const int t = threadIdx.x, w = t >> 6, l = t & 63, lr = l & 15, lg = l >> 4;
    const int nt = N >> 7;
    const int nwg = gridDim.x;
    const int bid = blockIdx.x;
    int wg = (nwg & 7) ? bid : ((bid & 7) * (nwg >> 3) + (bid >> 3));
    const int bm = wg / nt, bn = wg % nt;
    const int row0 = bm << 7, col0 = bn << 7;
    const int wr = w >> 1, wc = w & 1;

    f32x4 acc[4][4];
    #pragma unroll
    for (int i = 0; i < 4; i++)
        #pragma unroll
        for (int j = 0; j < 4; j++) acc[i][j] = (f32x4){0.f,0.f,0.f,0.f};

    const char* Ag = (const char*)(A + (size_t)(row0 + (t >> 2)) * K) + (t & 3) * 16;
    const char* Bg = (const char*)(Bt + (size_t)(col0 + (t >> 2)) * K) + (t & 3) * 16;
    const size_t rstep = (size_t)64 * K * 2;
    char* lAw = (char*)lA + w * 1024;
    char* lBw = (char*)lB + w * 1024;

    for (int k0 = 0; k0 < K; k0 += 32){
        size_t kb = (size_t)k0 * 2;
        gl_lds16(Ag + kb,          lAw);
        gl_lds16(Ag + kb + rstep,  lAw + 4096);
        gl_lds16(Bg + kb,          lBw);
        gl_lds16(Bg + kb + rstep,  lBw + 4096);
        __syncthreads();
        bf16x8 af[4], bfr[4];
        #pragma unroll
        for (int mi = 0; mi < 4; mi++)
            af[mi] = ldbf8(lA + (wr*64 + mi*16 + lr) * 32 + lg * 8);
        #pragma unroll
        for (int ni = 0; ni < 4; ni++)
            bfr[ni] = ldbf8(lB + (wc*64 + ni*16 + lr) * 32 + lg * 8);
        #pragma unroll
        for (int mi = 0; mi < 4; mi++)
            #pragma unroll
            for (int ni = 0; ni < 4; ni++)
                acc[mi][ni] = __builtin_amdgcn_mfma_f32_16x16x32_bf16(
                    af[mi], bfr[ni], acc[mi][ni], 0, 0, 0);
        __syncthreads();
    }

    float bcol[4];
    #pragma unroll
    for (int ni = 0; ni < 4; ni++) bcol[ni] = bias[col0 + wc*64 + ni*16 + lr];
    #pragma unroll
    for (int mi = 0; mi < 4; mi++){
        #pragma unroll
        for (int j = 0; j < 4; j++){
            int row = row0 + wr*64 + mi*16 + lg*4 + j;
            size_t base = (size_t)row * N + col0 + wc*64 + lr;
            #pragma unroll
            for (int ni = 0; ni < 4; ni++){
                float v = acc[mi][ni][j] + bcol[ni];
                size_t idx = base + (size_t)ni * 16;
                if (EPI == 0)      ((unsigned short*)outv)[idx] = f2bf(v);
                else if (EPI == 1) ((float*)outv)[idx] = v + resid[idx];
                else               ((unsigned short*)outv)[idx] = f2bf(gelu_tanh(v));
            }
        }
    }
}

// ---------------- 256x256 GEMM pieces
template<int MH>
__device__ __forceinline__ void gloadA(const unsigned short* bufA, bf16x8 (&af)[4][2],
                                       int wm, int lr, int sl0, int sl1){
    #pragma unroll
    for (int i = 0; i < 4; i++){
        int lrow = (wm*128 + (MH*4 + i)*16 + lr) * 64;
        af[i][0] = ldbf8(bufA + lrow + sl0);
        af[i][1] = ldbf8(bufA + lrow + sl1);
    }
}
__device__ __forceinline__ void gloadB(const unsigned short* bufB, bf16x8 (&bfr)[4][2],
                                       int wn, int lr, int sl0, int sl1){
    #pragma unroll
    for (int i = 0; i < 4; i++){
        int brow = (wn*64 + i*16 + lr) * 64;
        bfr[i][0] = ldbf8(bufB + brow + sl0);
        bfr[i][1] = ldbf8(bufB + brow + sl1);
    }
}
template<int MH, int NH>
__device__ __forceinline__ void gmma(const bf16x8 (&af)[4][2], const bf16x8 (&bfr)[4][2],
                                     f32x4 (&acc)[8][4]){
    #pragma unroll
    for (int i = 0; i < 4; i++)
        #pragma unroll
        for (int j = 0; j < 2; j++){
            f32x4& a = acc[MH*4 + i][NH*2 + j];
            a = __builtin_amdgcn_mfma_f32_16x16x32_bf16(af[i][0], bfr[NH*2+j][0], a, 0,0,0);
            a = __builtin_amdgcn_mfma_f32_16x16x32_bf16(af[i][1], bfr[NH*2+j][1], a, 0,0,0);
        }
}

// 256x256 K-loop: 2 barriers/tile, reads+MFMA free-scheduled (compiler lgkmcnt),
// double-buffered with counted vmcnt(2). chunk0 of tile t+2 issues after the
// bottom barrier (same buffer as tile t — barrier protects); chunks 1-3 of
// tile t+1 issue inside the compute region (other buffer — no hazard).
#define G256_LOOP(NT_, KBEG_)                                                   \
    for (int tk = 0; tk < (NT_); ++tk){                                         \
        const int cur = tk & 1;                                                 \
        const bool more1 = (tk + 1) < (NT_);                                    \
        const bool more2 = (tk + 2) < (NT_);                                    \
        const unsigned short* bufA = &lds[cur][0][0];                           \
        const unsigned short* bufB = &lds[cur][1][0];                           \
        if (more1) asm volatile("s_waitcnt vmcnt(2)" ::: "memory");             \
        else       asm volatile("s_waitcnt vmcnt(0)" ::: "memory");             \
        __builtin_amdgcn_s_barrier();                                           \
        {                                                                       \
            bf16x8 afr[4][2], bfr[4][2];                                        \
            gloadA<0>(bufA, afr, wm, lr, sl0, sl1);                             \
            gloadB(bufB, bfr, wn, lr, sl0, sl1);                                \
            if (more1){                                                         \
                stage(cur ^ 1, (KBEG_) + (tk + 1)*64, 1);                       \
                stage(cur ^ 1, (KBEG_) + (tk + 1)*64, 2);                       \
            }                                                                   \
            __builtin_amdgcn_s_setprio(1);                                      \
            gmma<0,0>(afr, bfr, acc);                                           \
            gmma<0,1>(afr, bfr, acc);                                           \
            __builtin_amdgcn_s_setprio(0);                                      \
            gloadA<1>(bufA, afr, wm, lr, sl0, sl1);                             \
            if (more1) stage(cur ^ 1, (KBEG_) + (tk + 1)*64, 3);                \
            __builtin_amdgcn_s_setprio(1);                                      \
            gmma<1,0>(afr, bfr, acc);                                           \
            gmma<1,1>(afr, bfr, acc);                                           \
            __builtin_amdgcn_s_setprio(0);                                      \
        }                                                                       \
        __builtin_amdgcn_s_barrier();                                           \
        if (more2) stage(cur, (KBEG_) + (tk + 2)*64, 0);                        \
    }

template<int EPI>  // 0: +bias->bf16 ; 2: +bias,gelu->bf16
__global__ __launch_bounds__(512, 1)
void gemm256(const unsigned short* __restrict__ A,
             const unsigned short* __restrict__ Bt,
             const float* __restrict__ bias,
             void* __restrict__ outv,
             int M, int N, int K){
    __shared__ unsigned short lds[2][2][256*64];
    const int t = threadIdx.x;
    const int w = t >> 6, l = t & 63, lr = l & 15, lg = l >> 4;
    const int wm = w >> 2, wn = w & 3;
    const int lr7 = lr & 7;
    const int sl0 = (lg ^ lr7) << 3;
    const int sl1 = ((4 + lg) ^ lr7) << 3;
    const int nbn = N >> 8;
    const int nwg = (M >> 8) * nbn;
    const int bid = blockIdx.x;
    const int wg = (nwg & 7) ? bid : ((bid & 7) * (nwg >> 3) + (bid >> 3));
    const int bm = wg / nbn, bn = wg % nbn;
    const size_t row0 = (size_t)bm << 8, col0 = (size_t)bn << 8;
    const int NT = K >> 6;

    f32x4 acc[8][4];
    #pragma unroll
    for (int i = 0; i < 8; i++)
        #pragma unroll
        for (int j = 0; j < 4; j++) acc[i][j] = (f32x4){0.f,0.f,0.f,0.f};

    int rowc[4], slogc[4];
    #pragma unroll
    for (int c = 0; c < 4; c++){
        int seg = t + (c << 9);
        rowc[c]  = seg >> 3;
        slogc[c] = (((seg & 7) ^ ((seg >> 3) & 7)) << 3);
    }
    const unsigned short* Abase = A  + row0 * K;
    const unsigned short* Bbase = Bt + col0 * K;
    auto stage = [&](int buf, int kofs, int c){
        int seg = t + (c << 9);
        const unsigned short* sa = Abase + (size_t)rowc[c] * K + kofs + slogc[c];
        const unsigned short* sb = Bbase + (size_t)rowc[c] * K + kofs + slogc[c];
        gl_lds16(sa, (void*)&lds[buf][0][seg * 8]);
        gl_lds16(sb, (void*)&lds[buf][1][seg * 8]);
    };

    #pragma unroll
    for (int c = 0; c < 4; c++) stage(0, 0, c);
    if (NT > 1) stage(1, 64, 0);

    G256_LOOP(NT, 0)

    float bcol[4];
    #pragma unroll
    for (int ni = 0; ni < 4; ni++) bcol[ni] = bias[col0 + wn*64 + ni*16 + lr];
    unsigned short* outp = (unsigned short*)outv;
    #pragma unroll
    for (int mi = 0; mi < 8; mi++){
        #pragma unroll
        for (int j = 0; j < 4; j++){
            size_t row = row0 + wm*128 + mi*16 + lg*4 + j;
            size_t base = row * N + col0 + wn*64 + lr;
            #pragma unroll
            for (int ni = 0; ni < 4; ni++){
                float v = acc[mi][ni][j] + bcol[ni];
                size_t idx = base + (size_t)ni * 16;
                if (EPI == 0) outp[idx] = f2bf(v);
                else          outp[idx] = f2bf(gelu_tanh(v));
            }
        }
    }
}

// ---------------- 256x256 split-K GEMM: grid = SK*(M/256)*(N/256); bf16 partials
__global__ __launch_bounds__(512, 1)
void gemm256sk(const unsigned short* __restrict__ A,
               const unsigned short* __restrict__ Bt,
               unsigned short* __restrict__ pout,
               int M, int N, int K, int klen){
    __shared__ unsigned short lds[2][2][256*64];
    const int t = threadIdx.x;
    const int w = t >> 6, l = t & 63, lr = l & 15, lg = l >> 4;
    const int wm = w >> 2, wn = w & 3;
    const int lr7 = lr & 7;
    const int sl0 = (lg ^ lr7) << 3;
    const int sl1 = ((4 + lg) ^ lr7) << 3;
    const int nbn = N >> 8;
    const int ntile = (M >> 8) * nbn;
    const int nwg = gridDim.x;
    const int bid = blockIdx.x;
    int wg = (nwg & 7) ? bid : ((bid & 7) * (nwg >> 3) + (bid >> 3));
    const int kh = wg / ntile;
    wg -= kh * ntile;
    const int bm = wg / nbn, bn = wg % nbn;
    const size_t row0 = (size_t)bm << 8, col0 = (size_t)bn << 8;
    const int NT = klen >> 6;
    const int kbeg = kh * klen;

    f32x4 acc[8][4];
    #pragma unroll
    for (int i = 0; i < 8; i++)
        #pragma unroll
        for (int j = 0; j < 4; j++) acc[i][j] = (f32x4){0.f,0.f,0.f,0.f};

    int rowc[4], slogc[4];
    #pragma unroll
    for (int c = 0; c < 4; c++){
        int seg = t + (c << 9);
        rowc[c]  = seg >> 3;
        slogc[c] = (((seg & 7) ^ ((seg >> 3) & 7)) << 3);
    }
    const unsigned short* Abase = A  + row0 * K;
    const unsigned short* Bbase = Bt + col0 * K;
    auto stage = [&](int buf, int kofs, int c){
        int seg = t + (c << 9);
        const unsigned short* sa = Abase + (size_t)rowc[c] * K + kofs + slogc[c];
        const unsigned short* sb = Bbase + (size_t)rowc[c] * K + kofs + slogc[c];
        gl_lds16(sa, (void*)&lds[buf][0][seg * 8]);
        gl_lds16(sb, (void*)&lds[buf][1][seg * 8]);
    };

    #pragma unroll
    for (int c = 0; c < 4; c++) stage(0, kbeg, c);
    if (NT > 1) stage(1, kbeg + 64, 0);

    G256_LOOP(NT, kbeg)

    unsigned short* outp = pout + (size_t)kh * M * N;
    #pragma unroll
    for (int mi = 0; mi < 8; mi++){
        #pragma unroll
        for (int j = 0; j < 4; j++){
            size_t row = row0 + wm*128 + mi*16 + lg*4 + j;
            size_t base = row * N + col0 + wn*64 + lr;
            #pragma unroll
            for (int ni = 0; ni < 4; ni++)
                outp[base + (size_t)ni * 16] = f2bf(acc[mi][ni][j]);
        }
    }
}

// ---------------- split-K x4 combine: out = sum(p[0..3]) + bias + resid (f32)
__global__ __launch_bounds__(256)
void combine_k4(const unsigned short* __restrict__ p,
                const float* __restrict__ bias, const float* __restrict__ resid,
                float* __restrict__ out){
    const size_t PS = (size_t)TM * TC;
    const int total = TM * TC / 4;
    for (int i = blockIdx.x * 256 + threadIdx.x; i < total; i += gridDim.x * 256){
        int e = i * 4;
        u16x4 a0 = *(const u16x4*)(p + e);
        u16x4 a1 = *(const u16x4*)(p + PS + e);
        u16x4 a2 = *(const u16x4*)(p + 2*PS + e);
        u16x4 a3 = *(const u16x4*)(p + 3*PS + e);
        float4 r = *(const float4*)(resid + e);
        float4 bb = *(const float4*)(bias + (e & (TC - 1)));
        float4 o;
        o.x = bf2f(a0[0]) + bf2f(a1[0]) + bf2f(a2[0]) + bf2f(a3[0]) + r.x + bb.x;
        o.y = bf2f(a0[1]) + bf2f(a1[1]) + bf2f(a2[1]) + bf2f(a3[1]) + r.y + bb.y;
        o.z = bf2f(a0[2]) + bf2f(a1[2]) + bf2f(a2[2]) + bf2f(a3[2]) + r.z + bb.z;
        o.w = bf2f(a0[3]) + bf2f(a1[3]) + bf2f(a2[3]) + bf2f(a3[3]) + r.w + bb.w;
        *(float4*)(out + e) = o;
    }
}

// ---------------- V pre-transpose: qkv [tok][3C] -> vTg [bh][kt][64 d][80]
__global__ __launch_bounds__(256)
void vtrans(const unsigned short* __restrict__ qkv, unsigned short* __restrict__ vTg){
    __shared__ unsigned short lt[64][68];
    int kt = blockIdx.x & (NQT - 1);
    int bh = blockIdx.x >> 5;
    int h = bh & (TH - 1), b = bh >> 4;
    int t = threadIdx.x;
    int r = t >> 2, c4 = t & 3;
    const unsigned short* src = qkv + (size_t)(b*TT + kt*64 + r) * (3*TC) + 2*TC + h*THD;
    u16x8 a0 = *(const u16x8*)(src + c4*8);
    u16x8 a1 = *(const u16x8*)(src + 32 + c4*8);
    #pragma unroll
    for (int j = 0; j < 8; j++){
        lt[r][c4*8 + j]      = a0[j];
        lt[r][32 + c4*8 + j] = a1[j];
    }
    __syncthreads();
    int d = t >> 2;
    unsigned short* dst = vTg + ((size_t)bh * NQT + kt) * (64*80) + (size_t)d * 80;
    u16x8 o0, o1;
    #pragma unroll
    for (int j = 0; j < 8; j++){
        o0[j] = lt[c4*8 + j][d];
        o1[j] = lt[32 + c4*8 + j][d];
    }
    *(u16x8*)(dst + c4*8)      = o0;
    *(u16x8*)(dst + 32 + c4*8) = o1;
}

// ---------------- flash attention (causal): 1024 blocks (bh x 32 q-tiles of 64 rows),
// 4 waves x 16 q-rows; KVBLK=128 staged to LDS; SWAPPED QK^T (mfma(K,Q) -> S^T)
__global__ __launch_bounds__(256, 3)
void attn_kernel(const unsigned short* __restrict__ qkv,
                 const unsigned short* __restrict__ vTg,
                 unsigned short* __restrict__ attn_out){
    __shared__ unsigned short kbuf[128*64];   // 16 KB (2 kv tiles)
    __shared__ unsigned short vbuf[128*64];   // 16 KB (2 V^T tiles)
    __shared__ unsigned short pl[4][16*136];  // 17.4 KB  (total ~49.4 KB -> 3/CU)

    const int bid = blockIdx.x;
    const int qrank = bid >> 5;          // 0..31, 0 = longest
    const int bh = bid & 31;
    const int h = bh & (TH - 1), b = bh >> 4;
    const int qb = 31 - qrank;           // q-tile (64 rows)
    const int q0 = qb << 6;
    const int t = threadIdx.x, w = t >> 6, l = t & 63, lr = l & 15, lg = l >> 4;
    const int lr7 = lr & 7;
    const int sl0 = (lg ^ lr7) << 3;
    const int sl1 = ((4 + lg) ^ lr7) << 3;
    const float SC = 0.18033688011112042f;   // 0.125 * log2(e)

    const int NP = (qb >> 1) + 1;            // kv pairs
    const int qrow_base = q0 + w*16;
    const int myq = qrow_base + lr;          // this thread's q-row (softmax state owner)

    // staging: 4 virtual 256-thread passes per operand; dest = vt*16B (lane-contig)
    const unsigned short* kgp[4];
    const unsigned short* vgp[4];
    #pragma unroll
    for (int p = 0; p < 4; p++){
        int vt = p*256 + t;
        int r  = vt >> 3;
        int sc = ((vt & 7) ^ (r & 7)) * 8;
        kgp[p] = qkv + (size_t)(b*TT + r) * (3*TC) + TC + h*THD + sc;
        vgp[p] = vTg + (size_t)bh * (NQT*64*80)
               + (size_t)(r >> 6) * (64*80) + (size_t)(r & 63) * 80 + sc;
    }
    const size_t kstep2 = (size_t)128 * (3*TC);   // 2 token-tiles
    const size_t vstep2 = (size_t)2 * (64*80);

    auto stage = [&](int pi){
        #pragma unroll
        for (int p = 0; p < 4; p++)
            gl_lds16(kgp[p] + (size_t)pi*kstep2, (void*)&kbuf[(p*256 + t)*8]);
        #pragma unroll
        for (int p = 0; p < 4; p++)
            gl_lds16(vgp[p] + (size_t)pi*vstep2, (void*)&vbuf[(p*256 + t)*8]);
    };

    const unsigned short* qr =
        qkv + (size_t)(b*TT + myq) * (3*TC) + h*THD;
    bf16x8 q0f = ldbf8(qr + lg*8), q1f = ldbf8(qr + 32 + lg*8);

    bf16x8 ones;
    #pragma unroll
    for (int i = 0; i < 8; i++) ones[i] = (__bf16)1.0f;

    f32x4 o[5];
    float m = -1e30f;   // running max (scaled/log2 domain) for q-row `myq`
    #pragma unroll
    for (int i = 0; i < 5; i++) o[i] = (f32x4){0.f,0.f,0.f,0.f};

    unsigned short* plw = &pl[w][0];

    stage(0);
    for (int pi = 0; pi < NP; ++pi){
        const int t0 = 2*pi, t1 = 2*pi + 1;
        asm volatile("s_waitcnt vmcnt(0)" ::: "memory");
        __builtin_amdgcn_s_barrier();

        // ---- S^T = K Q^T over 128 kv: s[cb][j] = S[kv = cb*16+lg*4+j][q = lr] ----
        f32x4 s[8];
        __builtin_amdgcn_s_setprio(1);
        #pragma unroll
        for (int cb = 0; cb < 8; cb++){
            bf16x8 ka = ldbf8(kbuf + (cb*16 + lr)*64 + sl0);
            bf16x8 kbf = ldbf8(kbuf + (cb*16 + lr)*64 + sl1);
            f32x4 z = (f32x4){0.f,0.f,0.f,0.f};
            z = __builtin_amdgcn_mfma_f32_16x16x32_bf16(ka, q0f, z, 0,0,0);
            z = __builtin_amdgcn_mfma_f32_16x16x32_bf16(kbf, q1f, z, 0,0,0);
            s[cb] = z;
        }
        __builtin_amdgcn_s_setprio(0);
        // ---- causal masks: kv_global = tile*64 + cb*16 + lg*4 + j vs q = myq ----
        if (t0 == qb){
            #pragma unroll
            for (int cb = 0; cb < 4; cb++)
                #pragma unroll
                for (int j = 0; j < 4; j++)
                    if (t0*64 + cb*16 + lg*4 + j > myq) s[cb][j] = -1e30f;
        }
        if (t1 == qb){
            #pragma unroll
            for (int cb = 4; cb < 8; cb++)
                #pragma unroll
                for (int j = 0; j < 4; j++)
                    if (t1*64 + (cb-4)*16 + lg*4 + j > myq) s[cb][j] = -1e30f;
        } else if (t1 > qb){
            #pragma unroll
            for (int cb = 4; cb < 8; cb++)
                #pragma unroll
                for (int j = 0; j < 4; j++) s[cb][j] = -1e30f;
        }
        // ---- row max: local 32-chain + 2-step cross-lane (lanes sharing lr) ----
        float mloc = s[0][0];
        #pragma unroll
        for (int cb = 0; cb < 8; cb++)
            #pragma unroll
            for (int j = 0; j < 4; j++) mloc = fmaxf(mloc, s[cb][j]);
        mloc = fmaxf(mloc, __shfl_xor(mloc, 16));
        mloc = fmaxf(mloc, __shfl_xor(mloc, 32));
        // ---- defer-max rescale (exact skip) ----
        bool grow = (mloc * SC > m);
        float al = 1.f;
        if (__any(grow)){
            float mn = fmaxf(m, mloc * SC);
            al = exp2f(m - mn);
            m = mn;
            float alb[4];
            #pragma unroll
            for (int j = 0; j < 4; j++) alb[j] = __shfl(al, lg*4 + j);
            #pragma unroll
            for (int db = 0; db < 5; db++)
                #pragma unroll
                for (int j = 0; j < 4; j++) o[db][j] *= alb[j];
        }
        // ---- P = exp2(s*SC - m), packed b64 writes: P[lr][cb*16 + lg*4 + 0..3] ----
        #pragma unroll
        for (int cb = 0; cb < 8; cb++){
            u16x4 pk;
            #pragma unroll
            for (int j = 0; j < 4; j++){
                float e = exp2f(__builtin_fmaf(s[cb][j], SC, -m));
                pk[j] = f2bf(e);
            }
            *(u16x4*)(plw + lr*136 + cb*16 + lg*4) = pk;
        }
        // ---- PV over both kv tiles ----
        bf16x8 pa0 = ldbf8(plw + lr*136 + lg*8);
        bf16x8 pa1 = ldbf8(plw + lr*136 + 32 + lg*8);
        bf16x8 pa2 = ldbf8(plw + lr*136 + 64 + lg*8);
        bf16x8 pa3 = ldbf8(plw + lr*136 + 96 + lg*8);
        __builtin_amdgcn_s_setprio(1);
        #pragma unroll
        for (int db = 0; db < 4; db++){
            bf16x8 v0a = ldbf8(vbuf + (db*16 + lr)*64 + sl0);
            bf16x8 v0b = ldbf8(vbuf + (db*16 + lr)*64 + sl1);
            o[db] = __builtin_amdgcn_mfma_f32_16x16x32_bf16(pa0, v0a, o[db], 0,0,0);
            o[db] = __builtin_amdgcn_mfma_f32_16x16x32_bf16(pa1, v0b, o[db], 0,0,0);
            bf16x8 v1a = ldbf8(vbuf + (64 + db*16 + lr)*64 + sl0);
            bf16x8 v1b = ldbf8(vbuf + (64 + db*16 + lr)*64 + sl1);
            o[db] = __builtin_amdgcn_mfma_f32_16x16x32_bf16(pa2, v1a, o[db], 0,0,0);
            o[db] = __builtin_amdgcn_mfma_f32_16x16x32_bf16(pa3, v1b, o[db], 0,0,0);
        }
        o[4] = __builtin_amdgcn_mfma_f32_16x16x32_bf16(pa0, ones, o[4], 0,0,0);
        o[4] = __builtin_amdgcn_mfma_f32_16x16x32_bf16(pa1, ones, o[4], 0,0,0);
        o[4] = __builtin_amdgcn_mfma_f32_16x16x32_bf16(pa2, ones, o[4], 0,0,0);
        o[4] = __builtin_amdgcn_mfma_f32_16x16x32_bf16(pa3, ones, o[4], 0,0,0);
        __builtin_amdgcn_s_setprio(0);

        __builtin_amdgcn_s_barrier();   // all reads done -> safe to overwrite buffers
        if (pi + 1 < NP) stage(pi + 1);
    }

    __bf16* aout = (__bf16*)attn_out;
    #pragma unroll
    for (int j = 0; j < 4; j++){
        float inv = 1.f / o[4][j];
        size_t tok = (size_t)(b*TT + qrow_base + lg*4 + j);
        #pragma unroll
        for (int db = 0; db < 4; db++)
            aout[tok*TC + h*THD + db*16 + lr] = (__bf16)(o[db][j] * inv);
    }
}

extern "C" void kernel_launch(void* const* d_in, const int* in_sizes, int n_in,
                              void* d_out, int out_size, void* d_ws, size_t ws_size,
                              hipStream_t stream){
    const float* x      = (const float*)d_in[0];
    const float* ln1_g  = (const float*)d_in[1];
    const float* ln1_b  = (const float*)d_in[2];
    const float* w_attn = (const float*)d_in[3];
    const float* b_attn = (const float*)d_in[4];
    const float* w_proj = (const float*)d_in[5];
    const float* b_proj = (const float*)d_in[6];
    const float* ln2_g  = (const float*)d_in[7];
    const float* ln2_b  = (const float*)d_in[8];
    const float* w_fc   = (const float*)d_in[9];
    const float* b_fc   = (const float*)d_in[10];
    const float* w_fc2  = (const float*)d_in[11];
    const float* b_fc2  = (const float*)d_in[12];
    float* out = (float*)d_out;

    char* ws = (char*)d_ws;
    size_t off = 0;
    auto alloc = [&](size_t bytes) -> void* {
        void* p = ws + off;
        off += (bytes + 255) & ~(size_t)255;
        return p;
    };
    unsigned short* wattnT = (unsigned short*)alloc((size_t)3072*1024*2);
    unsigned short* wprojT = (unsigned short*)alloc((size_t)1024*1024*2);
    unsigned short* wfcT   = (unsigned short*)alloc((size_t)4096*1024*2);
    unsigned short* wfc2T  = (unsigned short*)alloc((size_t)1024*4096*2);
    unsigned short* xn1    = (unsigned short*)alloc((size_t)TM*TC*2);    // + qkvb = split-K partial arena
    unsigned short* qkvb   = (unsigned short*)alloc((size_t)TM*3*TC*2);
    float*          resid1 = (float*)alloc((size_t)TM*TC*4);
    unsigned short* xn2    = (unsigned short*)alloc((size_t)TM*TC*2);
    unsigned short* hbuf   = (unsigned short*)alloc((size_t)TM*4*TC*2);
    unsigned short* attnO  = (unsigned short*)alloc((size_t)TM*TC*2);
    unsigned short* vTg    = (unsigned short*)alloc((size_t)TB*TH*NQT*64*80*2);

    unsigned short* pks = xn1;   // 4 x TM*TC bf16 = exactly xn1+qkvb (dead after attn)

    prep_all<<<12288 + TM, 256, 0, stream>>>(
        w_attn, w_proj, w_fc, w_fc2, wattnT, wprojT, wfcT, wfc2T,
        x, ln1_g, ln1_b, xn1);

    gemm256<0><<<(TM/256)*(3072/256), 512, 0, stream>>>(
        xn1, wattnT, b_attn, qkvb, TM, 3072, 1024);

    vtrans<<<TB*TH*NQT, 256, 0, stream>>>(qkvb, vTg);

    attn_kernel<<<TB*TH*NQT, 256, 0, stream>>>(qkvb, vTg, attnO);

    gemm_bt<1><<<(TM/128)*(1024/128), 256, 0, stream>>>(
        attnO, wprojT, b_proj, x, resid1, TM, 1024, 1024);

    ln_kernel<<<TM, 256, 0, stream>>>(resid1, ln2_g, ln2_b, xn2);

    gemm256<2><<<(TM/256)*(4096/256), 512, 0, stream>>>(
        xn2, wfcT, b_fc, hbuf, TM, 4096, 1024);

    // FC2: 256x256 split-K x4 (256 blocks = 1/CU), bf16 partials, then combine
    gemm256sk<<<4*(TM/256)*(1024/256), 512, 0, stream>>>(
        hbuf, wfc2T, pks, TM, 1024, 4096, 1024);
    combine_k4<<<2048, 256, 0, stream>>>(pks, b_fc2, resid1, out);
}

// Round 21
// 214.891 us; speedup vs baseline: 1.0011x; 1.0011x over previous
//
#include <hip/hip_runtime.h>
#include <math.h>

#define TB 2
#define TT 2048
#define TC 1024
#define TH 16
#define THD 64
#define TM (TB*TT)   // 4096 tokens
#define NQT 32       // TT/64 kv tiles

typedef __bf16 bf16x8 __attribute__((ext_vector_type(8)));
typedef float f32x4 __attribute__((ext_vector_type(4)));
typedef unsigned short u16x8 __attribute__((ext_vector_type(8)));
typedef unsigned short u16x4 __attribute__((ext_vector_type(4)));

__device__ __forceinline__ unsigned short f2bf(float f){
    unsigned int u = __builtin_bit_cast(unsigned int, f);
    u = (u + 0x7FFFu + ((u >> 16) & 1u)) >> 16;
    return (unsigned short)u;
}
__device__ __forceinline__ float bf2f(unsigned short h){
    unsigned int u = ((unsigned int)h) << 16;
    return __builtin_bit_cast(float, u);
}
__device__ __forceinline__ bf16x8 ldbf8(const unsigned short* p){
    return __builtin_bit_cast(bf16x8, *(const u16x8*)p);
}
__device__ __forceinline__ void gl_lds16(const void* g, void* l){
    __builtin_amdgcn_global_load_lds(
        (const __attribute__((address_space(1))) unsigned int*)g,
        (__attribute__((address_space(3))) unsigned int*)l,
        16, 0, 0);
}
__device__ __forceinline__ float gelu_tanh(float v){
    float u = 2.0f * 0.7978845608028654f * (v + 0.044715f * v * v * v);
    u = fminf(fmaxf(u, -30.f), 30.f);
    float e = __expf(u);
    return 0.5f * v * (1.f + (e - 1.f) / (e + 1.f));
}

// ---------------- prep: 4 weight convert+transposes AND ln1 in ONE kernel
__global__ __launch_bounds__(256)
void prep_all(const float* __restrict__ w_attn, const float* __restrict__ w_proj,
              const float* __restrict__ w_fc,   const float* __restrict__ w_fc2,
              unsigned short* __restrict__ wattnT, unsigned short* __restrict__ wprojT,
              unsigned short* __restrict__ wfcT,   unsigned short* __restrict__ wfc2T,
              const float* __restrict__ x, const float* __restrict__ ln1_g,
              const float* __restrict__ ln1_b, unsigned short* __restrict__ xn1){
    const int bid = blockIdx.x;
    const int t = threadIdx.x;
    if (bid >= 12288){
        const int row = bid - 12288;
        const float4* xr = (const float4*)(x + (size_t)row * TC);
        float4 v = xr[t];
        float s  = v.x + v.y + v.z + v.w;
        float s2 = v.x*v.x + v.y*v.y + v.z*v.z + v.w*v.w;
        #pragma unroll
        for (int off = 32; off; off >>= 1){
            s  += __shfl_down(s,  off);
            s2 += __shfl_down(s2, off);
        }
        __shared__ float red[8];
        int l = t & 63, wv = t >> 6;
        if (l == 0){ red[wv] = s; red[4 + wv] = s2; }
        __syncthreads();
        float S  = red[0] + red[1] + red[2] + red[3];
        float S2 = red[4] + red[5] + red[6] + red[7];
        float mu = S * (1.f / TC);
        float var = S2 * (1.f / TC) - mu * mu;
        float rs = rsqrtf(var + 1e-5f);
        int c = t * 4;
        float4 gg = *(const float4*)(ln1_g + c);
        float4 bb = *(const float4*)(ln1_b + c);
        u16x4 o;
        o[0] = f2bf((v.x - mu) * rs * gg.x + bb.x);
        o[1] = f2bf((v.y - mu) * rs * gg.y + bb.y);
        o[2] = f2bf((v.z - mu) * rs * gg.z + bb.z);
        o[3] = f2bf((v.w - mu) * rs * gg.w + bb.w);
        *(u16x4*)(xn1 + (size_t)row * TC + c) = o;
        return;
    }
    __shared__ float tile[32][33];
    const float* in; unsigned short* out; int K, N, bx, by;
    if (bid < 3072)      { in=w_attn; out=wattnT; K=1024; N=3072; bx=bid%96;  by=bid/96; }
    else if (bid < 4096) { int lo=bid-3072; in=w_proj; out=wprojT; K=1024; N=1024; bx=lo%32;  by=lo/32; }
    else if (bid < 8192) { int lo=bid-4096; in=w_fc;   out=wfcT;   K=1024; N=4096; bx=lo%128; by=lo/128; }
    else                 { int lo=bid-8192; in=w_fc2;  out=wfc2T;  K=4096; N=1024; bx=lo%32;  by=lo/32; }
    int tx = t & 31, ty = t >> 5;
    int n0 = bx * 32, k0 = by * 32;
    #pragma unroll
    for (int i = 0; i < 4; i++)
        tile[ty + 8*i][tx] = in[(size_t)(k0 + ty + 8*i) * N + n0 + tx];
    __syncthreads();
    #pragma unroll
    for (int i = 0; i < 4; i++)
        out[(size_t)(n0 + ty + 8*i) * K + k0 + tx] = f2bf(tile[tx][ty + 8*i]);
}

// ---------------- layernorm (ln2): x f32 [.][1024] -> y bf16
__global__ __launch_bounds__(256)
void ln_kernel(const float* __restrict__ x, const float* __restrict__ g,
               const float* __restrict__ be, unsigned short* __restrict__ y){
    const int row = blockIdx.x, t = threadIdx.x;
    const float4* xr = (const float4*)(x + (size_t)row * TC);
    float4 v = xr[t];
    float s  = v.x + v.y + v.z + v.w;
    float s2 = v.x*v.x + v.y*v.y + v.z*v.z + v.w*v.w;
    #pragma unroll
    for (int off = 32; off; off >>= 1){
        s  += __shfl_down(s,  off);
        s2 += __shfl_down(s2, off);
    }
    __shared__ float red[8];
    int l = t & 63, wv = t >> 6;
    if (l == 0){ red[wv] = s; red[4 + wv] = s2; }
    __syncthreads();
    float S  = red[0] + red[1] + red[2] + red[3];
    float S2 = red[4] + red[5] + red[6] + red[7];
    float mu = S * (1.f / TC);
    float var = S2 * (1.f / TC) - mu * mu;
    float rs = rsqrtf(var + 1e-5f);
    int c = t * 4;
    float4 gg = *(const float4*)(g + c);
    float4 bb = *(const float4*)(be + c);
    u16x4 o;
    o[0] = f2bf((v.x - mu) * rs * gg.x + bb.x);
    o[1] = f2bf((v.y - mu) * rs * gg.y + bb.y);
    o[2] = f2bf((v.z - mu) * rs * gg.z + bb.z);
    o[3] = f2bf((v.w - mu) * rs * gg.w + bb.w);
    *(u16x4*)(y + (size_t)row * TC + c) = o;
}

// ---------------- 128x128 GEMM (m97 structure) + XCD swizzle
// EPI 0: +bias->bf16 ; 1: +bias+resid->f32 ; 2: +bias,gelu->bf16
template<int EPI>
__global__ __launch_bounds__(256, 2)
void gemm_bt(const unsigned short* __restrict__ A,
             const unsigned short* __restrict__ Bt,
             const float* __restrict__ bias,
             const float* __restrict__ resid,
             void* __restrict__ outv,
             int M, int N, int K){
    __shared__ unsigned short lA[128 * 32];
    __shared__ unsigned short lB[128 * 32];
    const int t = threadIdx.x, w = t >> 6, l = t & 63, lr = l & 15, lg = l >> 4;
    const int nt = N >> 7;
    const int nwg = gridDim.x;
    const int bid = blockIdx.x;
    int wg = (nwg & 7) ? bid : ((bid & 7) * (nwg >> 3) + (bid >> 3));
    const int bm = wg / nt, bn = wg % nt;
    const int row0 = bm << 7, col0 = bn << 7;
    const int wr = w >> 1, wc = w & 1;

    f32x4 acc[4][4];
    #pragma unroll
    for (int i = 0; i < 4; i++)
        #pragma unroll
        for (int j = 0; j < 4; j++) acc[i][j] = (f32x4){0.f,0.f,0.f,0.f};

    const char* Ag = (const char*)(A + (size_t)(row0 + (t >> 2)) * K) + (t & 3) * 16;
    const char* Bg = (const char*)(Bt + (size_t)(col0 + (t >> 2)) * K) + (t & 3) * 16;
    const size_t rstep = (size_t)64 * K * 2;
    char* lAw = (char*)lA + w * 1024;
    char* lBw = (char*)lB + w * 1024;

    for (int k0 = 0; k0 < K; k0 += 32){
        size_t kb = (size_t)k0 * 2;
        gl_lds16(Ag + kb,          lAw);
        gl_lds16(Ag + kb + rstep,  lAw + 4096);
        gl_lds16(Bg + kb,          lBw);
        gl_lds16(Bg + kb + rstep,  lBw + 4096);
        __syncthreads();
        bf16x8 af[4], bfr[4];
        #pragma unroll
        for (int mi = 0; mi < 4; mi++)
            af[mi] = ldbf8(lA + (wr*64 + mi*16 + lr) * 32 + lg * 8);
        #pragma unroll
        for (int ni = 0; ni < 4; ni++)
            bfr[ni] = ldbf8(lB + (wc*64 + ni*16 + lr) * 32 + lg * 8);
        #pragma unroll
        for (int mi = 0; mi < 4; mi++)
            #pragma unroll
            for (int ni = 0; ni < 4; ni++)
                acc[mi][ni] = __builtin_amdgcn_mfma_f32_16x16x32_bf16(
                    af[mi], bfr[ni], acc[mi][ni], 0, 0, 0);
        __syncthreads();
    }

    float bcol[4];
    #pragma unroll
    for (int ni = 0; ni < 4; ni++) bcol[ni] = bias[col0 + wc*64 + ni*16 + lr];
    #pragma unroll
    for (int mi = 0; mi < 4; mi++){
        #pragma unroll
        for (int j = 0; j < 4; j++){
            int row = row0 + wr*64 + mi*16 + lg*4 + j;
            size_t base = (size_t)row * N + col0 + wc*64 + lr;
            #pragma unroll
            for (int ni = 0; ni < 4; ni++){
                float v = acc[mi][ni][j] + bcol[ni];
                size_t idx = base + (size_t)ni * 16;
                if (EPI == 0)      ((unsigned short*)outv)[idx] = f2bf(v);
                else if (EPI == 1) ((float*)outv)[idx] = v + resid[idx];
                else               ((unsigned short*)outv)[idx] = f2bf(gelu_tanh(v));
            }
        }
    }
}

// ---------------- 256x256 GEMM pieces
template<int MH>
__device__ __forceinline__ void gloadA(const unsigned short* bufA, bf16x8 (&af)[4][2],
                                       int wm, int lr, int sl0, int sl1){
    #pragma unroll
    for (int i = 0; i < 4; i++){
        int lrow = (wm*128 + (MH*4 + i)*16 + lr) * 64;
        af[i][0] = ldbf8(bufA + lrow + sl0);
        af[i][1] = ldbf8(bufA + lrow + sl1);
    }
}
__device__ __forceinline__ void gloadB(const unsigned short* bufB, bf16x8 (&bfr)[4][2],
                                       int wn, int lr, int sl0, int sl1){
    #pragma unroll
    for (int i = 0; i < 4; i++){
        int brow = (wn*64 + i*16 + lr) * 64;
        bfr[i][0] = ldbf8(bufB + brow + sl0);
        bfr[i][1] = ldbf8(bufB + brow + sl1);
    }
}
template<int MH, int NH>
__device__ __forceinline__ void gmma(const bf16x8 (&af)[4][2], const bf16x8 (&bfr)[4][2],
                                     f32x4 (&acc)[8][4]){
    #pragma unroll
    for (int i = 0; i < 4; i++)
        #pragma unroll
        for (int j = 0; j < 2; j++){
            f32x4& a = acc[MH*4 + i][NH*2 + j];
            a = __builtin_amdgcn_mfma_f32_16x16x32_bf16(af[i][0], bfr[NH*2+j][0], a, 0,0,0);
            a = __builtin_amdgcn_mfma_f32_16x16x32_bf16(af[i][1], bfr[NH*2+j][1], a, 0,0,0);
        }
}

// 256x256 K-loop: 2 barriers/tile, reads+MFMA free-scheduled (compiler lgkmcnt),
// double-buffered with counted vmcnt(2). chunk0 of tile t+2 issues after the
// bottom barrier (same buffer as tile t — barrier protects); chunks 1-3 of
// tile t+1 issue inside the compute region (other buffer — no hazard).
#define G256_LOOP(NT_, KBEG_)                                                   \
    for (int tk = 0; tk < (NT_); ++tk){                                         \
        const int cur = tk & 1;                                                 \
        const bool more1 = (tk + 1) < (NT_);                                    \
        const bool more2 = (tk + 2) < (NT_);                                    \
        const unsigned short* bufA = &lds[cur][0][0];                           \
        const unsigned short* bufB = &lds[cur][1][0];                           \
        if (more1) asm volatile("s_waitcnt vmcnt(2)" ::: "memory");             \
        else       asm volatile("s_waitcnt vmcnt(0)" ::: "memory");             \
        __builtin_amdgcn_s_barrier();                                           \
        {                                                                       \
            bf16x8 afr[4][2], bfr[4][2];                                        \
            gloadA<0>(bufA, afr, wm, lr, sl0, sl1);                             \
            gloadB(bufB, bfr, wn, lr, sl0, sl1);                                \
            if (more1){                                                         \
                stage(cur ^ 1, (KBEG_) + (tk + 1)*64, 1);                       \
                stage(cur ^ 1, (KBEG_) + (tk + 1)*64, 2);                       \
            }                                                                   \
            __builtin_amdgcn_s_setprio(1);                                      \
            gmma<0,0>(afr, bfr, acc);                                           \
            gmma<0,1>(afr, bfr, acc);                                           \
            __builtin_amdgcn_s_setprio(0);                                      \
            gloadA<1>(bufA, afr, wm, lr, sl0, sl1);                             \
            if (more1) stage(cur ^ 1, (KBEG_) + (tk + 1)*64, 3);                \
            __builtin_amdgcn_s_setprio(1);                                      \
            gmma<1,0>(afr, bfr, acc);                                           \
            gmma<1,1>(afr, bfr, acc);                                           \
            __builtin_amdgcn_s_setprio(0);                                      \
        }                                                                       \
        __builtin_amdgcn_s_barrier();                                           \
        if (more2) stage(cur, (KBEG_) + (tk + 2)*64, 0);                        \
    }

template<int EPI>  // 0: +bias->bf16 ; 2: +bias,gelu->bf16
__global__ __launch_bounds__(512, 1)
void gemm256(const unsigned short* __restrict__ A,
             const unsigned short* __restrict__ Bt,
             const float* __restrict__ bias,
             void* __restrict__ outv,
             int M, int N, int K){
    __shared__ unsigned short lds[2][2][256*64];
    const int t = threadIdx.x;
    const int w = t >> 6, l = t & 63, lr = l & 15, lg = l >> 4;
    const int wm = w >> 2, wn = w & 3;
    const int lr7 = lr & 7;
    const int sl0 = (lg ^ lr7) << 3;
    const int sl1 = ((4 + lg) ^ lr7) << 3;
    const int nbn = N >> 8;
    const int nwg = (M >> 8) * nbn;
    const int bid = blockIdx.x;
    const int wg = (nwg & 7) ? bid : ((bid & 7) * (nwg >> 3) + (bid >> 3));
    const int bm = wg / nbn, bn = wg % nbn;
    const size_t row0 = (size_t)bm << 8, col0 = (size_t)bn << 8;
    const int NT = K >> 6;

    f32x4 acc[8][4];
    #pragma unroll
    for (int i = 0; i < 8; i++)
        #pragma unroll
        for (int j = 0; j < 4; j++) acc[i][j] = (f32x4){0.f,0.f,0.f,0.f};

    int rowc[4], slogc[4];
    #pragma unroll
    for (int c = 0; c < 4; c++){
        int seg = t + (c << 9);
        rowc[c]  = seg >> 3;
        slogc[c] = (((seg & 7) ^ ((seg >> 3) & 7)) << 3);
    }
    const unsigned short* Abase = A  + row0 * K;
    const unsigned short* Bbase = Bt + col0 * K;
    auto stage = [&](int buf, int kofs, int c){
        int seg = t + (c << 9);
        const unsigned short* sa = Abase + (size_t)rowc[c] * K + kofs + slogc[c];
        const unsigned short* sb = Bbase + (size_t)rowc[c] * K + kofs + slogc[c];
        gl_lds16(sa, (void*)&lds[buf][0][seg * 8]);
        gl_lds16(sb, (void*)&lds[buf][1][seg * 8]);
    };

    #pragma unroll
    for (int c = 0; c < 4; c++) stage(0, 0, c);
    if (NT > 1) stage(1, 64, 0);

    G256_LOOP(NT, 0)

    float bcol[4];
    #pragma unroll
    for (int ni = 0; ni < 4; ni++) bcol[ni] = bias[col0 + wn*64 + ni*16 + lr];
    unsigned short* outp = (unsigned short*)outv;
    #pragma unroll
    for (int mi = 0; mi < 8; mi++){
        #pragma unroll
        for (int j = 0; j < 4; j++){
            size_t row = row0 + wm*128 + mi*16 + lg*4 + j;
            size_t base = row * N + col0 + wn*64 + lr;
            #pragma unroll
            for (int ni = 0; ni < 4; ni++){
                float v = acc[mi][ni][j] + bcol[ni];
                size_t idx = base + (size_t)ni * 16;
                if (EPI == 0) outp[idx] = f2bf(v);
                else          outp[idx] = f2bf(gelu_tanh(v));
            }
        }
    }
}

// ---------------- 256x256 split-K GEMM: grid = SK*(M/256)*(N/256); bf16 partials
__global__ __launch_bounds__(512, 1)
void gemm256sk(const unsigned short* __restrict__ A,
               const unsigned short* __restrict__ Bt,
               unsigned short* __restrict__ pout,
               int M, int N, int K, int klen){
    __shared__ unsigned short lds[2][2][256*64];
    const int t = threadIdx.x;
    const int w = t >> 6, l = t & 63, lr = l & 15, lg = l >> 4;
    const int wm = w >> 2, wn = w & 3;
    const int lr7 = lr & 7;
    const int sl0 = (lg ^ lr7) << 3;
    const int sl1 = ((4 + lg) ^ lr7) << 3;
    const int nbn = N >> 8;
    const int ntile = (M >> 8) * nbn;
    const int nwg = gridDim.x;
    const int bid = blockIdx.x;
    int wg = (nwg & 7) ? bid : ((bid & 7) * (nwg >> 3) + (bid >> 3));
    const int kh = wg / ntile;
    wg -= kh * ntile;
    const int bm = wg / nbn, bn = wg % nbn;
    const size_t row0 = (size_t)bm << 8, col0 = (size_t)bn << 8;
    const int NT = klen >> 6;
    const int kbeg = kh * klen;

    f32x4 acc[8][4];
    #pragma unroll
    for (int i = 0; i < 8; i++)
        #pragma unroll
        for (int j = 0; j < 4; j++) acc[i][j] = (f32x4){0.f,0.f,0.f,0.f};

    int rowc[4], slogc[4];
    #pragma unroll
    for (int c = 0; c < 4; c++){
        int seg = t + (c << 9);
        rowc[c]  = seg >> 3;
        slogc[c] = (((seg & 7) ^ ((seg >> 3) & 7)) << 3);
    }
    const unsigned short* Abase = A  + row0 * K;
    const unsigned short* Bbase = Bt + col0 * K;
    auto stage = [&](int buf, int kofs, int c){
        int seg = t + (c << 9);
        const unsigned short* sa = Abase + (size_t)rowc[c] * K + kofs + slogc[c];
        const unsigned short* sb = Bbase + (size_t)rowc[c] * K + kofs + slogc[c];
        gl_lds16(sa, (void*)&lds[buf][0][seg * 8]);
        gl_lds16(sb, (void*)&lds[buf][1][seg * 8]);
    };

    #pragma unroll
    for (int c = 0; c < 4; c++) stage(0, kbeg, c);
    if (NT > 1) stage(1, kbeg + 64, 0);

    G256_LOOP(NT, kbeg)

    unsigned short* outp = pout + (size_t)kh * M * N;
    #pragma unroll
    for (int mi = 0; mi < 8; mi++){
        #pragma unroll
        for (int j = 0; j < 4; j++){
            size_t row = row0 + wm*128 + mi*16 + lg*4 + j;
            size_t base = row * N + col0 + wn*64 + lr;
            #pragma unroll
            for (int ni = 0; ni < 4; ni++)
                outp[base + (size_t)ni * 16] = f2bf(acc[mi][ni][j]);
        }
    }
}

// ---------------- split-K x4 combine: out = sum(p[0..3]) + bias + resid (f32)
__global__ __launch_bounds__(256)
void combine_k4(const unsigned short* __restrict__ p,
                const float* __restrict__ bias, const float* __restrict__ resid,
                float* __restrict__ out){
    const size_t PS = (size_t)TM * TC;
    const int total = TM * TC / 4;
    for (int i = blockIdx.x * 256 + threadIdx.x; i < total; i += gridDim.x * 256){
        int e = i * 4;
        u16x4 a0 = *(const u16x4*)(p + e);
        u16x4 a1 = *(const u16x4*)(p + PS + e);
        u16x4 a2 = *(const u16x4*)(p + 2*PS + e);
        u16x4 a3 = *(const u16x4*)(p + 3*PS + e);
        float4 r = *(const float4*)(resid + e);
        float4 bb = *(const float4*)(bias + (e & (TC - 1)));
        float4 o;
        o.x = bf2f(a0[0]) + bf2f(a1[0]) + bf2f(a2[0]) + bf2f(a3[0]) + r.x + bb.x;
        o.y = bf2f(a0[1]) + bf2f(a1[1]) + bf2f(a2[1]) + bf2f(a3[1]) + r.y + bb.y;
        o.z = bf2f(a0[2]) + bf2f(a1[2]) + bf2f(a2[2]) + bf2f(a3[2]) + r.z + bb.z;
        o.w = bf2f(a0[3]) + bf2f(a1[3]) + bf2f(a2[3]) + bf2f(a3[3]) + r.w + bb.w;
        *(float4*)(out + e) = o;
    }
}

// ---------------- V pre-transpose: qkv [tok][3C] -> vTg [bh][kt][64 d][80]
__global__ __launch_bounds__(256)
void vtrans(const unsigned short* __restrict__ qkv, unsigned short* __restrict__ vTg){
    __shared__ unsigned short lt[64][68];
    int kt = blockIdx.x & (NQT - 1);
    int bh = blockIdx.x >> 5;
    int h = bh & (TH - 1), b = bh >> 4;
    int t = threadIdx.x;
    int r = t >> 2, c4 = t & 3;
    const unsigned short* src = qkv + (size_t)(b*TT + kt*64 + r) * (3*TC) + 2*TC + h*THD;
    u16x8 a0 = *(const u16x8*)(src + c4*8);
    u16x8 a1 = *(const u16x8*)(src + 32 + c4*8);
    #pragma unroll
    for (int j = 0; j < 8; j++){
        lt[r][c4*8 + j]      = a0[j];
        lt[r][32 + c4*8 + j] = a1[j];
    }
    __syncthreads();
    int d = t >> 2;
    unsigned short* dst = vTg + ((size_t)bh * NQT + kt) * (64*80) + (size_t)d * 80;
    u16x8 o0, o1;
    #pragma unroll
    for (int j = 0; j < 8; j++){
        o0[j] = lt[c4*8 + j][d];
        o1[j] = lt[32 + c4*8 + j][d];
    }
    *(u16x8*)(dst + c4*8)      = o0;
    *(u16x8*)(dst + 32 + c4*8) = o1;
}

// ---------------- flash attention (causal): 1024 blocks (bh x 32 q-tiles of 64 rows),
// 4 waves x 16 q-rows; KVBLK=128 staged to LDS; SWAPPED QK^T (mfma(K,Q) -> S^T)
__global__ __launch_bounds__(256, 3)
void attn_kernel(const unsigned short* __restrict__ qkv,
                 const unsigned short* __restrict__ vTg,
                 unsigned short* __restrict__ attn_out){
    __shared__ unsigned short kbuf[128*64];   // 16 KB (2 kv tiles)
    __shared__ unsigned short vbuf[128*64];   // 16 KB (2 V^T tiles)
    __shared__ unsigned short pl[4][16*136];  // 17.4 KB  (total ~49.4 KB -> 3/CU)

    const int bid = blockIdx.x;
    const int qrank = bid >> 5;          // 0..31, 0 = longest
    const int bh = bid & 31;
    const int h = bh & (TH - 1), b = bh >> 4;
    const int qb = 31 - qrank;           // q-tile (64 rows)
    const int q0 = qb << 6;
    const int t = threadIdx.x, w = t >> 6, l = t & 63, lr = l & 15, lg = l >> 4;
    const int lr7 = lr & 7;
    const int sl0 = (lg ^ lr7) << 3;
    const int sl1 = ((4 + lg) ^ lr7) << 3;
    const float SC = 0.18033688011112042f;   // 0.125 * log2(e)

    const int NP = (qb >> 1) + 1;            // kv pairs
    const int qrow_base = q0 + w*16;
    const int myq = qrow_base + lr;          // this thread's q-row (softmax state owner)

    // staging: 4 virtual 256-thread passes per operand; dest = vt*16B (lane-contig)
    const unsigned short* kgp[4];
    const unsigned short* vgp[4];
    #pragma unroll
    for (int p = 0; p < 4; p++){
        int vt = p*256 + t;
        int r  = vt >> 3;
        int sc = ((vt & 7) ^ (r & 7)) * 8;
        kgp[p] = qkv + (size_t)(b*TT + r) * (3*TC) + TC + h*THD + sc;
        vgp[p] = vTg + (size_t)bh * (NQT*64*80)
               + (size_t)(r >> 6) * (64*80) + (size_t)(r & 63) * 80 + sc;
    }
    const size_t kstep2 = (size_t)128 * (3*TC);   // 2 token-tiles
    const size_t vstep2 = (size_t)2 * (64*80);

    auto stage = [&](int pi){
        #pragma unroll
        for (int p = 0; p < 4; p++)
            gl_lds16(kgp[p] + (size_t)pi*kstep2, (void*)&kbuf[(p*256 + t)*8]);
        #pragma unroll
        for (int p = 0; p < 4; p++)
            gl_lds16(vgp[p] + (size_t)pi*vstep2, (void*)&vbuf[(p*256 + t)*8]);
    };

    const unsigned short* qr =
        qkv + (size_t)(b*TT + myq) * (3*TC) + h*THD;
    bf16x8 q0f = ldbf8(qr + lg*8), q1f = ldbf8(qr + 32 + lg*8);

    bf16x8 ones;
    #pragma unroll
    for (int i = 0; i < 8; i++) ones[i] = (__bf16)1.0f;

    f32x4 o[5];
    float m = -1e30f;   // running max (scaled/log2 domain) for q-row `myq`
    #pragma unroll
    for (int i = 0; i < 5; i++) o[i] = (f32x4){0.f,0.f,0.f,0.f};

    unsigned short* plw = &pl[w][0];

    stage(0);
    for (int pi = 0; pi < NP; ++pi){
        const int t0 = 2*pi, t1 = 2*pi + 1;
        asm volatile("s_waitcnt vmcnt(0)" ::: "memory");
        __builtin_amdgcn_s_barrier();

        // ---- S^T = K Q^T over 128 kv: s[cb][j] = S[kv = cb*16+lg*4+j][q = lr] ----
        f32x4 s[8];
        __builtin_amdgcn_s_setprio(1);
        #pragma unroll
        for (int cb = 0; cb < 8; cb++){
            bf16x8 ka = ldbf8(kbuf + (cb*16 + lr)*64 + sl0);
            bf16x8 kbf = ldbf8(kbuf + (cb*16 + lr)*64 + sl1);
            f32x4 z = (f32x4){0.f,0.f,0.f,0.f};
            z = __builtin_amdgcn_mfma_f32_16x16x32_bf16(ka, q0f, z, 0,0,0);
            z = __builtin_amdgcn_mfma_f32_16x16x32_bf16(kbf, q1f, z, 0,0,0);
            s[cb] = z;
        }
        __builtin_amdgcn_s_setprio(0);
        // ---- causal masks: kv_global = tile*64 + cb*16 + lg*4 + j vs q = myq ----
        if (t0 == qb){
            #pragma unroll
            for (int cb = 0; cb < 4; cb++)
                #pragma unroll
                for (int j = 0; j < 4; j++)
                    if (t0*64 + cb*16 + lg*4 + j > myq) s[cb][j] = -1e30f;
        }
        if (t1 == qb){
            #pragma unroll
            for (int cb = 4; cb < 8; cb++)
                #pragma unroll
                for (int j = 0; j < 4; j++)
                    if (t1*64 + (cb-4)*16 + lg*4 + j > myq) s[cb][j] = -1e30f;
        } else if (t1 > qb){
            #pragma unroll
            for (int cb = 4; cb < 8; cb++)
                #pragma unroll
                for (int j = 0; j < 4; j++) s[cb][j] = -1e30f;
        }
        // ---- row max: local 32-chain + 2-step cross-lane (lanes sharing lr) ----
        float mloc = s[0][0];
        #pragma unroll
        for (int cb = 0; cb < 8; cb++)
            #pragma unroll
            for (int j = 0; j < 4; j++) mloc = fmaxf(mloc, s[cb][j]);
        mloc = fmaxf(mloc, __shfl_xor(mloc, 16));
        mloc = fmaxf(mloc, __shfl_xor(mloc, 32));
        // ---- defer-max rescale (exact skip) ----
        bool grow = (mloc * SC > m);
        float al = 1.f;
        if (__any(grow)){
            float mn = fmaxf(m, mloc * SC);
            al = exp2f(m - mn);
            m = mn;
            float alb[4];
            #pragma unroll
            for (int j = 0; j < 4; j++) alb[j] = __shfl(al, lg*4 + j);
            #pragma unroll
            for (int db = 0; db < 5; db++)
                #pragma unroll
                for (int j = 0; j < 4; j++) o[db][j] *= alb[j];
        }
        // ---- P = exp2(s*SC - m), packed b64 writes: P[lr][cb*16 + lg*4 + 0..3] ----
        #pragma unroll
        for (int cb = 0; cb < 8; cb++){
            u16x4 pk;
            #pragma unroll
            for (int j = 0; j < 4; j++){
                float e = exp2f(__builtin_fmaf(s[cb][j], SC, -m));
                pk[j] = f2bf(e);
            }
            *(u16x4*)(plw + lr*136 + cb*16 + lg*4) = pk;
        }
        // ---- PV over both kv tiles ----
        bf16x8 pa0 = ldbf8(plw + lr*136 + lg*8);
        bf16x8 pa1 = ldbf8(plw + lr*136 + 32 + lg*8);
        bf16x8 pa2 = ldbf8(plw + lr*136 + 64 + lg*8);
        bf16x8 pa3 = ldbf8(plw + lr*136 + 96 + lg*8);
        __builtin_amdgcn_s_setprio(1);
        #pragma unroll
        for (int db = 0; db < 4; db++){
            bf16x8 v0a = ldbf8(vbuf + (db*16 + lr)*64 + sl0);
            bf16x8 v0b = ldbf8(vbuf + (db*16 + lr)*64 + sl1);
            o[db] = __builtin_amdgcn_mfma_f32_16x16x32_bf16(pa0, v0a, o[db], 0,0,0);
            o[db] = __builtin_amdgcn_mfma_f32_16x16x32_bf16(pa1, v0b, o[db], 0,0,0);
            bf16x8 v1a = ldbf8(vbuf + (64 + db*16 + lr)*64 + sl0);
            bf16x8 v1b = ldbf8(vbuf + (64 + db*16 + lr)*64 + sl1);
            o[db] = __builtin_amdgcn_mfma_f32_16x16x32_bf16(pa2, v1a, o[db], 0,0,0);
            o[db] = __builtin_amdgcn_mfma_f32_16x16x32_bf16(pa3, v1b, o[db], 0,0,0);
        }
        o[4] = __builtin_amdgcn_mfma_f32_16x16x32_bf16(pa0, ones, o[4], 0,0,0);
        o[4] = __builtin_amdgcn_mfma_f32_16x16x32_bf16(pa1, ones, o[4], 0,0,0);
        o[4] = __builtin_amdgcn_mfma_f32_16x16x32_bf16(pa2, ones, o[4], 0,0,0);
        o[4] = __builtin_amdgcn_mfma_f32_16x16x32_bf16(pa3, ones, o[4], 0,0,0);
        __builtin_amdgcn_s_setprio(0);

        __builtin_amdgcn_s_barrier();   // all reads done -> safe to overwrite buffers
        if (pi + 1 < NP) stage(pi + 1);
    }

    __bf16* aout = (__bf16*)attn_out;
    #pragma unroll
    for (int j = 0; j < 4; j++){
        float inv = 1.f / o[4][j];
        size_t tok = (size_t)(b*TT + qrow_base + lg*4 + j);
        #pragma unroll
        for (int db = 0; db < 4; db++)
            aout[tok*TC + h*THD + db*16 + lr] = (__bf16)(o[db][j] * inv);
    }
}

extern "C" void kernel_launch(void* const* d_in, const int* in_sizes, int n_in,
                              void* d_out, int out_size, void* d_ws, size_t ws_size,
                              hipStream_t stream){
    const float* x      = (const float*)d_in[0];
    const float* ln1_g  = (const float*)d_in[1];
    const float* ln1_b  = (const float*)d_in[2];
    const float* w_attn = (const float*)d_in[3];
    const float* b_attn = (const float*)d_in[4];
    const float* w_proj = (const float*)d_in[5];
    const float* b_proj = (const float*)d_in[6];
    const float* ln2_g  = (const float*)d_in[7];
    const float* ln2_b  = (const float*)d_in[8];
    const float* w_fc   = (const float*)d_in[9];
    const float* b_fc   = (const float*)d_in[10];
    const float* w_fc2  = (const float*)d_in[11];
    const float* b_fc2  = (const float*)d_in[12];
    float* out = (float*)d_out;

    char* ws = (char*)d_ws;
    size_t off = 0;
    auto alloc = [&](size_t bytes) -> void* {
        void* p = ws + off;
        off += (bytes + 255) & ~(size_t)255;
        return p;
    };
    unsigned short* wattnT = (unsigned short*)alloc((size_t)3072*1024*2);
    unsigned short* wprojT = (unsigned short*)alloc((size_t)1024*1024*2);
    unsigned short* wfcT   = (unsigned short*)alloc((size_t)4096*1024*2);
    unsigned short* wfc2T  = (unsigned short*)alloc((size_t)1024*4096*2);
    unsigned short* xn1    = (unsigned short*)alloc((size_t)TM*TC*2);    // + qkvb = split-K partial arena
    unsigned short* qkvb   = (unsigned short*)alloc((size_t)TM*3*TC*2);
    float*          resid1 = (float*)alloc((size_t)TM*TC*4);
    unsigned short* xn2    = (unsigned short*)alloc((size_t)TM*TC*2);
    unsigned short* hbuf   = (unsigned short*)alloc((size_t)TM*4*TC*2);
    unsigned short* attnO  = (unsigned short*)alloc((size_t)TM*TC*2);
    unsigned short* vTg    = (unsigned short*)alloc((size_t)TB*TH*NQT*64*80*2);

    unsigned short* pks = xn1;   // 4 x TM*TC bf16 = exactly xn1+qkvb (dead after attn)

    prep_all<<<12288 + TM, 256, 0, stream>>>(
        w_attn, w_proj, w_fc, w_fc2, wattnT, wprojT, wfcT, wfc2T,
        x, ln1_g, ln1_b, xn1);

    gemm256<0><<<(TM/256)*(3072/256), 512, 0, stream>>>(
        xn1, wattnT, b_attn, qkvb, TM, 3072, 1024);

    vtrans<<<TB*TH*NQT, 256, 0, stream>>>(qkvb, vTg);

    attn_kernel<<<TB*TH*NQT, 256, 0, stream>>>(qkvb, vTg, attnO);

    gemm_bt<1><<<(TM/128)*(1024/128), 256, 0, stream>>>(
        attnO, wprojT, b_proj, x, resid1, TM, 1024, 1024);

    ln_kernel<<<TM, 256, 0, stream>>>(resid1, ln2_g, ln2_b, xn2);

    gemm256<2><<<(TM/256)*(4096/256), 512, 0, stream>>>(
        xn2, wfcT, b_fc, hbuf, TM, 4096, 1024);

    // FC2: 256x256 split-K x4 (256 blocks = 1/CU), bf16 partials, then combine
    gemm256sk<<<4*(TM/256)*(1024/256), 512, 0, stream>>>(
        hbuf, wfc2T, pks, TM, 1024, 4096, 1024);
    combine_k4<<<2048, 256, 0, stream>>>(pks, b_fc2, resid1, out);
}

// Round 22
// 213.949 us; speedup vs baseline: 1.0055x; 1.0044x over previous
//
#include <hip/hip_runtime.h>
#include <math.h>

#define TB 2
#define TT 2048
#define TC 1024
#define TH 16
#define THD 64
#define TM (TB*TT)   // 4096 tokens
#define NQT 32       // TT/64 kv tiles

typedef __bf16 bf16x8 __attribute__((ext_vector_type(8)));
typedef float f32x4 __attribute__((ext_vector_type(4)));
typedef unsigned short u16x8 __attribute__((ext_vector_type(8)));
typedef unsigned short u16x4 __attribute__((ext_vector_type(4)));

__device__ __forceinline__ unsigned short f2bf(float f){
    unsigned int u = __builtin_bit_cast(unsigned int, f);
    u = (u + 0x7FFFu + ((u >> 16) & 1u)) >> 16;
    return (unsigned short)u;
}
__device__ __forceinline__ float bf2f(unsigned short h){
    unsigned int u = ((unsigned int)h) << 16;
    return __builtin_bit_cast(float, u);
}
__device__ __forceinline__ bf16x8 ldbf8(const unsigned short* p){
    return __builtin_bit_cast(bf16x8, *(const u16x8*)p);
}
__device__ __forceinline__ void gl_lds16(const void* g, void* l){
    __builtin_amdgcn_global_load_lds(
        (const __attribute__((address_space(1))) unsigned int*)g,
        (__attribute__((address_space(3))) unsigned int*)l,
        16, 0, 0);
}
__device__ __forceinline__ float gelu_tanh(float v){
    float u = 2.0f * 0.7978845608028654f * (v + 0.044715f * v * v * v);
    u = fminf(fmaxf(u, -30.f), 30.f);
    float e = __expf(u);
    return 0.5f * v * (1.f + (e - 1.f) / (e + 1.f));
}

// ---------------- prep: 4 weight convert+transposes AND ln1 in ONE kernel
__global__ __launch_bounds__(256)
void prep_all(const float* __restrict__ w_attn, const float* __restrict__ w_proj,
              const float* __restrict__ w_fc,   const float* __restrict__ w_fc2,
              unsigned short* __restrict__ wattnT, unsigned short* __restrict__ wprojT,
              unsigned short* __restrict__ wfcT,   unsigned short* __restrict__ wfc2T,
              const float* __restrict__ x, const float* __restrict__ ln1_g,
              const float* __restrict__ ln1_b, unsigned short* __restrict__ xn1){
    const int bid = blockIdx.x;
    const int t = threadIdx.x;
    if (bid >= 12288){
        const int row = bid - 12288;
        const float4* xr = (const float4*)(x + (size_t)row * TC);
        float4 v = xr[t];
        float s  = v.x + v.y + v.z + v.w;
        float s2 = v.x*v.x + v.y*v.y + v.z*v.z + v.w*v.w;
        #pragma unroll
        for (int off = 32; off; off >>= 1){
            s  += __shfl_down(s,  off);
            s2 += __shfl_down(s2, off);
        }
        __shared__ float red[8];
        int l = t & 63, wv = t >> 6;
        if (l == 0){ red[wv] = s; red[4 + wv] = s2; }
        __syncthreads();
        float S  = red[0] + red[1] + red[2] + red[3];
        float S2 = red[4] + red[5] + red[6] + red[7];
        float mu = S * (1.f / TC);
        float var = S2 * (1.f / TC) - mu * mu;
        float rs = rsqrtf(var + 1e-5f);
        int c = t * 4;
        float4 gg = *(const float4*)(ln1_g + c);
        float4 bb = *(const float4*)(ln1_b + c);
        u16x4 o;
        o[0] = f2bf((v.x - mu) * rs * gg.x + bb.x);
        o[1] = f2bf((v.y - mu) * rs * gg.y + bb.y);
        o[2] = f2bf((v.z - mu) * rs * gg.z + bb.z);
        o[3] = f2bf((v.w - mu) * rs * gg.w + bb.w);
        *(u16x4*)(xn1 + (size_t)row * TC + c) = o;
        return;
    }
    __shared__ float tile[32][33];
    const float* in; unsigned short* out; int K, N, bx, by;
    if (bid < 3072)      { in=w_attn; out=wattnT; K=1024; N=3072; bx=bid%96;  by=bid/96; }
    else if (bid < 4096) { int lo=bid-3072; in=w_proj; out=wprojT; K=1024; N=1024; bx=lo%32;  by=lo/32; }
    else if (bid < 8192) { int lo=bid-4096; in=w_fc;   out=wfcT;   K=1024; N=4096; bx=lo%128; by=lo/128; }
    else                 { int lo=bid-8192; in=w_fc2;  out=wfc2T;  K=4096; N=1024; bx=lo%32;  by=lo/32; }
    int tx = t & 31, ty = t >> 5;
    int n0 = bx * 32, k0 = by * 32;
    #pragma unroll
    for (int i = 0; i < 4; i++)
        tile[ty + 8*i][tx] = in[(size_t)(k0 + ty + 8*i) * N + n0 + tx];
    __syncthreads();
    #pragma unroll
    for (int i = 0; i < 4; i++)
        out[(size_t)(n0 + ty + 8*i) * K + k0 + tx] = f2bf(tile[tx][ty + 8*i]);
}

// ---------------- layernorm (ln2): x f32 [.][1024] -> y bf16
__global__ __launch_bounds__(256)
void ln_kernel(const float* __restrict__ x, const float* __restrict__ g,
               const float* __restrict__ be, unsigned short* __restrict__ y){
    const int row = blockIdx.x, t = threadIdx.x;
    const float4* xr = (const float4*)(x + (size_t)row * TC);
    float4 v = xr[t];
    float s  = v.x + v.y + v.z + v.w;
    float s2 = v.x*v.x + v.y*v.y + v.z*v.z + v.w*v.w;
    #pragma unroll
    for (int off = 32; off; off >>= 1){
        s  += __shfl_down(s,  off);
        s2 += __shfl_down(s2, off);
    }
    __shared__ float red[8];
    int l = t & 63, wv = t >> 6;
    if (l == 0){ red[wv] = s; red[4 + wv] = s2; }
    __syncthreads();
    float S  = red[0] + red[1] + red[2] + red[3];
    float S2 = red[4] + red[5] + red[6] + red[7];
    float mu = S * (1.f / TC);
    float var = S2 * (1.f / TC) - mu * mu;
    float rs = rsqrtf(var + 1e-5f);
    int c = t * 4;
    float4 gg = *(const float4*)(g + c);
    float4 bb = *(const float4*)(be + c);
    u16x4 o;
    o[0] = f2bf((v.x - mu) * rs * gg.x + bb.x);
    o[1] = f2bf((v.y - mu) * rs * gg.y + bb.y);
    o[2] = f2bf((v.z - mu) * rs * gg.z + bb.z);
    o[3] = f2bf((v.w - mu) * rs * gg.w + bb.w);
    *(u16x4*)(y + (size_t)row * TC + c) = o;
}

// ---------------- 128x128 GEMM (m97 structure) + XCD swizzle
// EPI 0: +bias->bf16 ; 1: +bias+resid->f32 ; 2: +bias,gelu->bf16
template<int EPI>
__global__ __launch_bounds__(256, 2)
void gemm_bt(const unsigned short* __restrict__ A,
             const unsigned short* __restrict__ Bt,
             const float* __restrict__ bias,
             const float* __restrict__ resid,
             void* __restrict__ outv,
             int M, int N, int K){
    __shared__ unsigned short lA[128 * 32];
    __shared__ unsigned short lB[128 * 32];
    const int t = threadIdx.x, w = t >> 6, l = t & 63, lr = l & 15, lg = l >> 4;
    const int nt = N >> 7;
    const int nwg = gridDim.x;
    const int bid = blockIdx.x;
    int wg = (nwg & 7) ? bid : ((bid & 7) * (nwg >> 3) + (bid >> 3));
    const int bm = wg / nt, bn = wg % nt;
    const int row0 = bm << 7, col0 = bn << 7;
    const int wr = w >> 1, wc = w & 1;

    f32x4 acc[4][4];
    #pragma unroll
    for (int i = 0; i < 4; i++)
        #pragma unroll
        for (int j = 0; j < 4; j++) acc[i][j] = (f32x4){0.f,0.f,0.f,0.f};

    const char* Ag = (const char*)(A + (size_t)(row0 + (t >> 2)) * K) + (t & 3) * 16;
    const char* Bg = (const char*)(Bt + (size_t)(col0 + (t >> 2)) * K) + (t & 3) * 16;
    const size_t rstep = (size_t)64 * K * 2;
    char* lAw = (char*)lA + w * 1024;
    char* lBw = (char*)lB + w * 1024;

    for (int k0 = 0; k0 < K; k0 += 32){
        size_t kb = (size_t)k0 * 2;
        gl_lds16(Ag + kb,          lAw);
        gl_lds16(Ag + kb + rstep,  lAw + 4096);
        gl_lds16(Bg + kb,          lBw);
        gl_lds16(Bg + kb + rstep,  lBw + 4096);
        __syncthreads();
        bf16x8 af[4], bfr[4];
        #pragma unroll
        for (int mi = 0; mi < 4; mi++)
            af[mi] = ldbf8(lA + (wr*64 + mi*16 + lr) * 32 + lg * 8);
        #pragma unroll
        for (int ni = 0; ni < 4; ni++)
            bfr[ni] = ldbf8(lB + (wc*64 + ni*16 + lr) * 32 + lg * 8);
        #pragma unroll
        for (int mi = 0; mi < 4; mi++)
            #pragma unroll
            for (int ni = 0; ni < 4; ni++)
                acc[mi][ni] = __builtin_amdgcn_mfma_f32_16x16x32_bf16(
                    af[mi], bfr[ni], acc[mi][ni], 0, 0, 0);
        __syncthreads();
    }

    float bcol[4];
    #pragma unroll
    for (int ni = 0; ni < 4; ni++) bcol[ni] = bias[col0 + wc*64 + ni*16 + lr];
    #pragma unroll
    for (int mi = 0; mi < 4; mi++){
        #pragma unroll
        for (int j = 0; j < 4; j++){
            int row = row0 + wr*64 + mi*16 + lg*4 + j;
            size_t base = (size_t)row * N + col0 + wc*64 + lr;
            #pragma unroll
            for (int ni = 0; ni < 4; ni++){
                float v = acc[mi][ni][j] + bcol[ni];
                size_t idx = base + (size_t)ni * 16;
                if (EPI == 0)      ((unsigned short*)outv)[idx] =
                    __builtin_bit_cast(unsigned short, (__bf16)v);
                else if (EPI == 1) ((float*)outv)[idx] = v + resid[idx];
                else               ((unsigned short*)outv)[idx] =
                    __builtin_bit_cast(unsigned short, (__bf16)gelu_tanh(v));
            }
        }
    }
}

// ---------------- 256x256 GEMM pieces
template<int MH>
__device__ __forceinline__ void gloadA(const unsigned short* bufA, bf16x8 (&af)[4][2],
                                       int wm, int lr, int sl0, int sl1){
    #pragma unroll
    for (int i = 0; i < 4; i++){
        int lrow = (wm*128 + (MH*4 + i)*16 + lr) * 64;
        af[i][0] = ldbf8(bufA + lrow + sl0);
        af[i][1] = ldbf8(bufA + lrow + sl1);
    }
}
__device__ __forceinline__ void gloadB(const unsigned short* bufB, bf16x8 (&bfr)[4][2],
                                       int wn, int lr, int sl0, int sl1){
    #pragma unroll
    for (int i = 0; i < 4; i++){
        int brow = (wn*64 + i*16 + lr) * 64;
        bfr[i][0] = ldbf8(bufB + brow + sl0);
        bfr[i][1] = ldbf8(bufB + brow + sl1);
    }
}
template<int MH, int NH>
__device__ __forceinline__ void gmma(const bf16x8 (&af)[4][2], const bf16x8 (&bfr)[4][2],
                                     f32x4 (&acc)[8][4]){
    #pragma unroll
    for (int i = 0; i < 4; i++)
        #pragma unroll
        for (int j = 0; j < 2; j++){
            f32x4& a = acc[MH*4 + i][NH*2 + j];
            a = __builtin_amdgcn_mfma_f32_16x16x32_bf16(af[i][0], bfr[NH*2+j][0], a, 0,0,0);
            a = __builtin_amdgcn_mfma_f32_16x16x32_bf16(af[i][1], bfr[NH*2+j][1], a, 0,0,0);
        }
}

// 256x256 K-loop: 2 barriers/tile, reads+MFMA free-scheduled (compiler lgkmcnt),
// double-buffered with counted vmcnt(2).
#define G256_LOOP(NT_, KBEG_)                                                   \
    for (int tk = 0; tk < (NT_); ++tk){                                         \
        const int cur = tk & 1;                                                 \
        const bool more1 = (tk + 1) < (NT_);                                    \
        const bool more2 = (tk + 2) < (NT_);                                    \
        const unsigned short* bufA = &lds[cur][0][0];                           \
        const unsigned short* bufB = &lds[cur][1][0];                           \
        if (more1) asm volatile("s_waitcnt vmcnt(2)" ::: "memory");             \
        else       asm volatile("s_waitcnt vmcnt(0)" ::: "memory");             \
        __builtin_amdgcn_s_barrier();                                           \
        {                                                                       \
            bf16x8 afr[4][2], bfr[4][2];                                        \
            gloadA<0>(bufA, afr, wm, lr, sl0, sl1);                             \
            gloadB(bufB, bfr, wn, lr, sl0, sl1);                                \
            if (more1){                                                         \
                stage(cur ^ 1, (KBEG_) + (tk + 1)*64, 1);                       \
                stage(cur ^ 1, (KBEG_) + (tk + 1)*64, 2);                       \
            }                                                                   \
            __builtin_amdgcn_s_setprio(1);                                      \
            gmma<0,0>(afr, bfr, acc);                                           \
            gmma<0,1>(afr, bfr, acc);                                           \
            __builtin_amdgcn_s_setprio(0);                                      \
            gloadA<1>(bufA, afr, wm, lr, sl0, sl1);                             \
            if (more1) stage(cur ^ 1, (KBEG_) + (tk + 1)*64, 3);                \
            __builtin_amdgcn_s_setprio(1);                                      \
            gmma<1,0>(afr, bfr, acc);                                           \
            gmma<1,1>(afr, bfr, acc);                                           \
            __builtin_amdgcn_s_setprio(0);                                      \
        }                                                                       \
        __builtin_amdgcn_s_barrier();                                           \
        if (more2) stage(cur, (KBEG_) + (tk + 2)*64, 0);                        \
    }

template<int EPI>  // 0: +bias->bf16 ; 2: +bias,gelu->bf16
__global__ __launch_bounds__(512, 1)
void gemm256(const unsigned short* __restrict__ A,
             const unsigned short* __restrict__ Bt,
             const float* __restrict__ bias,
             void* __restrict__ outv,
             int M, int N, int K){
    __shared__ unsigned short lds[2][2][256*64];
    const int t = threadIdx.x;
    const int w = t >> 6, l = t & 63, lr = l & 15, lg = l >> 4;
    const int wm = w >> 2, wn = w & 3;
    const int lr7 = lr & 7;
    const int sl0 = (lg ^ lr7) << 3;
    const int sl1 = ((4 + lg) ^ lr7) << 3;
    const int nbn = N >> 8;
    const int nwg = (M >> 8) * nbn;
    const int bid = blockIdx.x;
    const int wg = (nwg & 7) ? bid : ((bid & 7) * (nwg >> 3) + (bid >> 3));
    const int bm = wg / nbn, bn = wg % nbn;
    const size_t row0 = (size_t)bm << 8, col0 = (size_t)bn << 8;
    const int NT = K >> 6;

    f32x4 acc[8][4];
    #pragma unroll
    for (int i = 0; i < 8; i++)
        #pragma unroll
        for (int j = 0; j < 4; j++) acc[i][j] = (f32x4){0.f,0.f,0.f,0.f};

    int rowc[4], slogc[4];
    #pragma unroll
    for (int c = 0; c < 4; c++){
        int seg = t + (c << 9);
        rowc[c]  = seg >> 3;
        slogc[c] = (((seg & 7) ^ ((seg >> 3) & 7)) << 3);
    }
    const unsigned short* Abase = A  + row0 * K;
    const unsigned short* Bbase = Bt + col0 * K;
    auto stage = [&](int buf, int kofs, int c){
        int seg = t + (c << 9);
        const unsigned short* sa = Abase + (size_t)rowc[c] * K + kofs + slogc[c];
        const unsigned short* sb = Bbase + (size_t)rowc[c] * K + kofs + slogc[c];
        gl_lds16(sa, (void*)&lds[buf][0][seg * 8]);
        gl_lds16(sb, (void*)&lds[buf][1][seg * 8]);
    };

    #pragma unroll
    for (int c = 0; c < 4; c++) stage(0, 0, c);
    if (NT > 1) stage(1, 64, 0);

    G256_LOOP(NT, 0)

    float bcol[4];
    #pragma unroll
    for (int ni = 0; ni < 4; ni++) bcol[ni] = bias[col0 + wn*64 + ni*16 + lr];
    unsigned short* outp = (unsigned short*)outv;
    #pragma unroll
    for (int mi = 0; mi < 8; mi++){
        #pragma unroll
        for (int j = 0; j < 4; j++){
            size_t row = row0 + wm*128 + mi*16 + lg*4 + j;
            size_t base = row * N + col0 + wn*64 + lr;
            #pragma unroll
            for (int ni = 0; ni < 4; ni++){
                float v = acc[mi][ni][j] + bcol[ni];
                size_t idx = base + (size_t)ni * 16;
                if (EPI == 0) outp[idx] = __builtin_bit_cast(unsigned short, (__bf16)v);
                else          outp[idx] = __builtin_bit_cast(unsigned short, (__bf16)gelu_tanh(v));
            }
        }
    }
}

// ---------------- 256x256 split-K GEMM: grid = SK*(M/256)*(N/256); bf16 partials
__global__ __launch_bounds__(512, 1)
void gemm256sk(const unsigned short* __restrict__ A,
               const unsigned short* __restrict__ Bt,
               unsigned short* __restrict__ pout,
               int M, int N, int K, int klen){
    __shared__ unsigned short lds[2][2][256*64];
    const int t = threadIdx.x;
    const int w = t >> 6, l = t & 63, lr = l & 15, lg = l >> 4;
    const int wm = w >> 2, wn = w & 3;
    const int lr7 = lr & 7;
    const int sl0 = (lg ^ lr7) << 3;
    const int sl1 = ((4 + lg) ^ lr7) << 3;
    const int nbn = N >> 8;
    const int ntile = (M >> 8) * nbn;
    const int nwg = gridDim.x;
    const int bid = blockIdx.x;
    int wg = (nwg & 7) ? bid : ((bid & 7) * (nwg >> 3) + (bid >> 3));
    const int kh = wg / ntile;
    wg -= kh * ntile;
    const int bm = wg / nbn, bn = wg % nbn;
    const size_t row0 = (size_t)bm << 8, col0 = (size_t)bn << 8;
    const int NT = klen >> 6;
    const int kbeg = kh * klen;

    f32x4 acc[8][4];
    #pragma unroll
    for (int i = 0; i < 8; i++)
        #pragma unroll
        for (int j = 0; j < 4; j++) acc[i][j] = (f32x4){0.f,0.f,0.f,0.f};

    int rowc[4], slogc[4];
    #pragma unroll
    for (int c = 0; c < 4; c++){
        int seg = t + (c << 9);
        rowc[c]  = seg >> 3;
        slogc[c] = (((seg & 7) ^ ((seg >> 3) & 7)) << 3);
    }
    const unsigned short* Abase = A  + row0 * K;
    const unsigned short* Bbase = Bt + col0 * K;
    auto stage = [&](int buf, int kofs, int c){
        int seg = t + (c << 9);
        const unsigned short* sa = Abase + (size_t)rowc[c] * K + kofs + slogc[c];
        const unsigned short* sb = Bbase + (size_t)rowc[c] * K + kofs + slogc[c];
        gl_lds16(sa, (void*)&lds[buf][0][seg * 8]);
        gl_lds16(sb, (void*)&lds[buf][1][seg * 8]);
    };

    #pragma unroll
    for (int c = 0; c < 4; c++) stage(0, kbeg, c);
    if (NT > 1) stage(1, kbeg + 64, 0);

    G256_LOOP(NT, kbeg)

    unsigned short* outp = pout + (size_t)kh * M * N;
    #pragma unroll
    for (int mi = 0; mi < 8; mi++){
        #pragma unroll
        for (int j = 0; j < 4; j++){
            size_t row = row0 + wm*128 + mi*16 + lg*4 + j;
            size_t base = row * N + col0 + wn*64 + lr;
            #pragma unroll
            for (int ni = 0; ni < 4; ni++)
                outp[base + (size_t)ni * 16] =
                    __builtin_bit_cast(unsigned short, (__bf16)acc[mi][ni][j]);
        }
    }
}

// ---------------- split-K x4 combine: out = sum(p[0..3]) + bias + resid (f32)
__global__ __launch_bounds__(256)
void combine_k4(const unsigned short* __restrict__ p,
                const float* __restrict__ bias, const float* __restrict__ resid,
                float* __restrict__ out){
    const size_t PS = (size_t)TM * TC;
    const int total = TM * TC / 4;
    for (int i = blockIdx.x * 256 + threadIdx.x; i < total; i += gridDim.x * 256){
        int e = i * 4;
        u16x4 a0 = *(const u16x4*)(p + e);
        u16x4 a1 = *(const u16x4*)(p + PS + e);
        u16x4 a2 = *(const u16x4*)(p + 2*PS + e);
        u16x4 a3 = *(const u16x4*)(p + 3*PS + e);
        float4 r = *(const float4*)(resid + e);
        float4 bb = *(const float4*)(bias + (e & (TC - 1)));
        float4 o;
        o.x = bf2f(a0[0]) + bf2f(a1[0]) + bf2f(a2[0]) + bf2f(a3[0]) + r.x + bb.x;
        o.y = bf2f(a0[1]) + bf2f(a1[1]) + bf2f(a2[1]) + bf2f(a3[1]) + r.y + bb.y;
        o.z = bf2f(a0[2]) + bf2f(a1[2]) + bf2f(a2[2]) + bf2f(a3[2]) + r.z + bb.z;
        o.w = bf2f(a0[3]) + bf2f(a1[3]) + bf2f(a2[3]) + bf2f(a3[3]) + r.w + bb.w;
        *(float4*)(out + e) = o;
    }
}

// ---------------- V pre-transpose: qkv [tok][3C] -> vTg [bh][kt][64 d][80]
__global__ __launch_bounds__(256)
void vtrans(const unsigned short* __restrict__ qkv, unsigned short* __restrict__ vTg){
    __shared__ unsigned short lt[64][68];
    int kt = blockIdx.x & (NQT - 1);
    int bh = blockIdx.x >> 5;
    int h = bh & (TH - 1), b = bh >> 4;
    int t = threadIdx.x;
    int r = t >> 2, c4 = t & 3;
    const unsigned short* src = qkv + (size_t)(b*TT + kt*64 + r) * (3*TC) + 2*TC + h*THD;
    u16x8 a0 = *(const u16x8*)(src + c4*8);
    u16x8 a1 = *(const u16x8*)(src + 32 + c4*8);
    #pragma unroll
    for (int j = 0; j < 8; j++){
        lt[r][c4*8 + j]      = a0[j];
        lt[r][32 + c4*8 + j] = a1[j];
    }
    __syncthreads();
    int d = t >> 2;
    unsigned short* dst = vTg + ((size_t)bh * NQT + kt) * (64*80) + (size_t)d * 80;
    u16x8 o0, o1;
    #pragma unroll
    for (int j = 0; j < 8; j++){
        o0[j] = lt[c4*8 + j][d];
        o1[j] = lt[32 + c4*8 + j][d];
    }
    *(u16x8*)(dst + c4*8)      = o0;
    *(u16x8*)(dst + 32 + c4*8) = o1;
}

// ---------------- flash attention (causal): 1024 blocks (bh x 32 q-tiles of 64 rows),
// 4 waves x 16 q-rows; KVBLK=128 staged to LDS; SWAPPED QK^T (mfma(K,Q) -> S^T);
// native bf16 cvt_pk for P-pack; P stride 144 (read conflicts 4-way)
__global__ __launch_bounds__(256, 3)
void attn_kernel(const unsigned short* __restrict__ qkv,
                 const unsigned short* __restrict__ vTg,
                 unsigned short* __restrict__ attn_out){
    __shared__ unsigned short kbuf[128*64];   // 16 KB (2 kv tiles)
    __shared__ unsigned short vbuf[128*64];   // 16 KB (2 V^T tiles)
    __shared__ unsigned short pl[4][16*144];  // 18.4 KB  (total ~50.4 KB -> 3/CU)

    const int bid = blockIdx.x;
    const int qrank = bid >> 5;          // 0..31, 0 = longest
    const int bh = bid & 31;
    const int h = bh & (TH - 1), b = bh >> 4;
    const int qb = 31 - qrank;           // q-tile (64 rows)
    const int q0 = qb << 6;
    const int t = threadIdx.x, w = t >> 6, l = t & 63, lr = l & 15, lg = l >> 4;
    const int lr7 = lr & 7;
    const int sl0 = (lg ^ lr7) << 3;
    const int sl1 = ((4 + lg) ^ lr7) << 3;
    const float SC = 0.18033688011112042f;   // 0.125 * log2(e)

    const int NP = (qb >> 1) + 1;            // kv pairs
    const int qrow_base = q0 + w*16;
    const int myq = qrow_base + lr;          // this thread's q-row (softmax state owner)

    // staging: 4 virtual 256-thread passes per operand; dest = vt*16B (lane-contig)
    const unsigned short* kgp[4];
    const unsigned short* vgp[4];
    #pragma unroll
    for (int p = 0; p < 4; p++){
        int vt = p*256 + t;
        int r  = vt >> 3;
        int sc = ((vt & 7) ^ (r & 7)) * 8;
        kgp[p] = qkv + (size_t)(b*TT + r) * (3*TC) + TC + h*THD + sc;
        vgp[p] = vTg + (size_t)bh * (NQT*64*80)
               + (size_t)(r >> 6) * (64*80) + (size_t)(r & 63) * 80 + sc;
    }
    const size_t kstep2 = (size_t)128 * (3*TC);   // 2 token-tiles
    const size_t vstep2 = (size_t)2 * (64*80);

    auto stage = [&](int pi){
        #pragma unroll
        for (int p = 0; p < 4; p++)
            gl_lds16(kgp[p] + (size_t)pi*kstep2, (void*)&kbuf[(p*256 + t)*8]);
        #pragma unroll
        for (int p = 0; p < 4; p++)
            gl_lds16(vgp[p] + (size_t)pi*vstep2, (void*)&vbuf[(p*256 + t)*8]);
    };

    const unsigned short* qr =
        qkv + (size_t)(b*TT + myq) * (3*TC) + h*THD;
    bf16x8 q0f = ldbf8(qr + lg*8), q1f = ldbf8(qr + 32 + lg*8);

    bf16x8 ones;
    #pragma unroll
    for (int i = 0; i < 8; i++) ones[i] = (__bf16)1.0f;

    f32x4 o[5];
    float m = -1e30f;   // running max (scaled/log2 domain) for q-row `myq`
    #pragma unroll
    for (int i = 0; i < 5; i++) o[i] = (f32x4){0.f,0.f,0.f,0.f};

    unsigned short* plw = &pl[w][0];

    stage(0);
    for (int pi = 0; pi < NP; ++pi){
        const int t0 = 2*pi, t1 = 2*pi + 1;
        asm volatile("s_waitcnt vmcnt(0)" ::: "memory");
        __builtin_amdgcn_s_barrier();

        // ---- S^T = K Q^T over 128 kv: s[cb][j] = S[kv = cb*16+lg*4+j][q = lr] ----
        f32x4 s[8];
        __builtin_amdgcn_s_setprio(1);
        #pragma unroll
        for (int cb = 0; cb < 8; cb++){
            bf16x8 ka = ldbf8(kbuf + (cb*16 + lr)*64 + sl0);
            bf16x8 kbf = ldbf8(kbuf + (cb*16 + lr)*64 + sl1);
            f32x4 z = (f32x4){0.f,0.f,0.f,0.f};
            z = __builtin_amdgcn_mfma_f32_16x16x32_bf16(ka, q0f, z, 0,0,0);
            z = __builtin_amdgcn_mfma_f32_16x16x32_bf16(kbf, q1f, z, 0,0,0);
            s[cb] = z;
        }
        __builtin_amdgcn_s_setprio(0);
        // ---- causal masks: kv_global = tile*64 + cb*16 + lg*4 + j vs q = myq ----
        if (t0 == qb){
            #pragma unroll
            for (int cb = 0; cb < 4; cb++)
                #pragma unroll
                for (int j = 0; j < 4; j++)
                    if (t0*64 + cb*16 + lg*4 + j > myq) s[cb][j] = -1e30f;
        }
        if (t1 == qb){
            #pragma unroll
            for (int cb = 4; cb < 8; cb++)
                #pragma unroll
                for (int j = 0; j < 4; j++)
                    if (t1*64 + (cb-4)*16 + lg*4 + j > myq) s[cb][j] = -1e30f;
        } else if (t1 > qb){
            #pragma unroll
            for (int cb = 4; cb < 8; cb++)
                #pragma unroll
                for (int j = 0; j < 4; j++) s[cb][j] = -1e30f;
        }
        // ---- row max: local 32-chain + 2-step cross-lane (lanes sharing lr) ----
        float mloc = s[0][0];
        #pragma unroll
        for (int cb = 0; cb < 8; cb++)
            #pragma unroll
            for (int j = 0; j < 4; j++) mloc = fmaxf(mloc, s[cb][j]);
        mloc = fmaxf(mloc, __shfl_xor(mloc, 16));
        mloc = fmaxf(mloc, __shfl_xor(mloc, 32));
        // ---- defer-max rescale (exact skip) ----
        bool grow = (mloc * SC > m);
        float al = 1.f;
        if (__any(grow)){
            float mn = fmaxf(m, mloc * SC);
            al = exp2f(m - mn);
            m = mn;
            float alb[4];
            #pragma unroll
            for (int j = 0; j < 4; j++) alb[j] = __shfl(al, lg*4 + j);
            #pragma unroll
            for (int db = 0; db < 5; db++)
                #pragma unroll
                for (int j = 0; j < 4; j++) o[db][j] *= alb[j];
        }
        // ---- P = exp2(s*SC - m), native bf16 casts (cvt_pk), packed b64 writes ----
        #pragma unroll
        for (int cb = 0; cb < 8; cb++){
            u16x4 pk;
            #pragma unroll
            for (int j = 0; j < 4; j++){
                float e = exp2f(__builtin_fmaf(s[cb][j], SC, -m));
                pk[j] = __builtin_bit_cast(unsigned short, (__bf16)e);
            }
            *(u16x4*)(plw + lr*144 + cb*16 + lg*4) = pk;
        }
        // ---- PV over both kv tiles ----
        bf16x8 pa0 = ldbf8(plw + lr*144 + lg*8);
        bf16x8 pa1 = ldbf8(plw + lr*144 + 32 + lg*8);
        bf16x8 pa2 = ldbf8(plw + lr*144 + 64 + lg*8);
        bf16x8 pa3 = ldbf8(plw + lr*144 + 96 + lg*8);
        __builtin_amdgcn_s_setprio(1);
        #pragma unroll
        for (int db = 0; db < 4; db++){
            bf16x8 v0a = ldbf8(vbuf + (db*16 + lr)*64 + sl0);
            bf16x8 v0b = ldbf8(vbuf + (db*16 + lr)*64 + sl1);
            o[db] = __builtin_amdgcn_mfma_f32_16x16x32_bf16(pa0, v0a, o[db], 0,0,0);
            o[db] = __builtin_amdgcn_mfma_f32_16x16x32_bf16(pa1, v0b, o[db], 0,0,0);
            bf16x8 v1a = ldbf8(vbuf + (64 + db*16 + lr)*64 + sl0);
            bf16x8 v1b = ldbf8(vbuf + (64 + db*16 + lr)*64 + sl1);
            o[db] = __builtin_amdgcn_mfma_f32_16x16x32_bf16(pa2, v1a, o[db], 0,0,0);
            o[db] = __builtin_amdgcn_mfma_f32_16x16x32_bf16(pa3, v1b, o[db], 0,0,0);
        }
        o[4] = __builtin_amdgcn_mfma_f32_16x16x32_bf16(pa0, ones, o[4], 0,0,0);
        o[4] = __builtin_amdgcn_mfma_f32_16x16x32_bf16(pa1, ones, o[4], 0,0,0);
        o[4] = __builtin_amdgcn_mfma_f32_16x16x32_bf16(pa2, ones, o[4], 0,0,0);
        o[4] = __builtin_amdgcn_mfma_f32_16x16x32_bf16(pa3, ones, o[4], 0,0,0);
        __builtin_amdgcn_s_setprio(0);

        __builtin_amdgcn_s_barrier();   // all reads done -> safe to overwrite buffers
        if (pi + 1 < NP) stage(pi + 1);
    }

    __bf16* aout = (__bf16*)attn_out;
    #pragma unroll
    for (int j = 0; j < 4; j++){
        float inv = 1.f / o[4][j];
        size_t tok = (size_t)(b*TT + qrow_base + lg*4 + j);
        #pragma unroll
        for (int db = 0; db < 4; db++)
            aout[tok*TC + h*THD + db*16 + lr] = (__bf16)(o[db][j] * inv);
    }
}

extern "C" void kernel_launch(void* const* d_in, const int* in_sizes, int n_in,
                              void* d_out, int out_size, void* d_ws, size_t ws_size,
                              hipStream_t stream){
    const float* x      = (const float*)d_in[0];
    const float* ln1_g  = (const float*)d_in[1];
    const float* ln1_b  = (const float*)d_in[2];
    const float* w_attn = (const float*)d_in[3];
    const float* b_attn = (const float*)d_in[4];
    const float* w_proj = (const float*)d_in[5];
    const float* b_proj = (const float*)d_in[6];
    const float* ln2_g  = (const float*)d_in[7];
    const float* ln2_b  = (const float*)d_in[8];
    const float* w_fc   = (const float*)d_in[9];
    const float* b_fc   = (const float*)d_in[10];
    const float* w_fc2  = (const float*)d_in[11];
    const float* b_fc2  = (const float*)d_in[12];
    float* out = (float*)d_out;

    char* ws = (char*)d_ws;
    size_t off = 0;
    auto alloc = [&](size_t bytes) -> void* {
        void* p = ws + off;
        off += (bytes + 255) & ~(size_t)255;
        return p;
    };
    unsigned short* wattnT = (unsigned short*)alloc((size_t)3072*1024*2);
    unsigned short* wprojT = (unsigned short*)alloc((size_t)1024*1024*2);
    unsigned short* wfcT   = (unsigned short*)alloc((size_t)4096*1024*2);
    unsigned short* wfc2T  = (unsigned short*)alloc((size_t)1024*4096*2);
    unsigned short* xn1    = (unsigned short*)alloc((size_t)TM*TC*2);    // + qkvb = split-K partial arena
    unsigned short* qkvb   = (unsigned short*)alloc((size_t)TM*3*TC*2);
    float*          resid1 = (float*)alloc((size_t)TM*TC*4);
    unsigned short* xn2    = (unsigned short*)alloc((size_t)TM*TC*2);
    unsigned short* hbuf   = (unsigned short*)alloc((size_t)TM*4*TC*2);
    unsigned short* attnO  = (unsigned short*)alloc((size_t)TM*TC*2);
    unsigned short* vTg    = (unsigned short*)alloc((size_t)TB*TH*NQT*64*80*2);

    unsigned short* pks = xn1;   // 4 x TM*TC bf16 = exactly xn1+qkvb (dead after attn)

    prep_all<<<12288 + TM, 256, 0, stream>>>(
        w_attn, w_proj, w_fc, w_fc2, wattnT, wprojT, wfcT, wfc2T,
        x, ln1_g, ln1_b, xn1);

    gemm256<0><<<(TM/256)*(3072/256), 512, 0, stream>>>(
        xn1, wattnT, b_attn, qkvb, TM, 3072, 1024);

    vtrans<<<TB*TH*NQT, 256, 0, stream>>>(qkvb, vTg);

    attn_kernel<<<TB*TH*NQT, 256, 0, stream>>>(qkvb, vTg, attnO);

    gemm_bt<1><<<(TM/128)*(1024/128), 256, 0, stream>>>(
        attnO, wprojT, b_proj, x, resid1, TM, 1024, 1024);

    ln_kernel<<<TM, 256, 0, stream>>>(resid1, ln2_g, ln2_b, xn2);

    gemm256<2><<<(TM/256)*(4096/256), 512, 0, stream>>>(
        xn2, wfcT, b_fc, hbuf, TM, 4096, 1024);

    // FC2: 256x256 split-K x4 (256 blocks = 1/CU), bf16 partials, then combine
    gemm256sk<<<4*(TM/256)*(1024/256), 512, 0, stream>>>(
        hbuf, wfc2T, pks, TM, 1024, 4096, 1024);
    combine_k4<<<2048, 256, 0, stream>>>(pks, b_fc2, resid1, out);
}

// Round 23
// 213.765 us; speedup vs baseline: 1.0064x; 1.0009x over previous
//
#include <hip/hip_runtime.h>
#include <math.h>

#define TB 2
#define TT 2048
#define TC 1024
#define TH 16
#define THD 64
#define TM (TB*TT)   // 4096 tokens
#define NQT 32       // TT/64 kv tiles

typedef __bf16 bf16x8 __attribute__((ext_vector_type(8)));
typedef float f32x4 __attribute__((ext_vector_type(4)));
typedef unsigned short u16x8 __attribute__((ext_vector_type(8)));
typedef unsigned short u16x4 __attribute__((ext_vector_type(4)));

__device__ __forceinline__ unsigned short f2bf(float f){
    unsigned int u = __builtin_bit_cast(unsigned int, f);
    u = (u + 0x7FFFu + ((u >> 16) & 1u)) >> 16;
    return (unsigned short)u;
}
__device__ __forceinline__ float bf2f(unsigned short h){
    unsigned int u = ((unsigned int)h) << 16;
    return __builtin_bit_cast(float, u);
}
__device__ __forceinline__ bf16x8 ldbf8(const unsigned short* p){
    return __builtin_bit_cast(bf16x8, *(const u16x8*)p);
}
__device__ __forceinline__ void gl_lds16(const void* g, void* l){
    __builtin_amdgcn_global_load_lds(
        (const __attribute__((address_space(1))) unsigned int*)g,
        (__attribute__((address_space(3))) unsigned int*)l,
        16, 0, 0);
}
__device__ __forceinline__ float gelu_tanh(float v){
    float u = 2.0f * 0.7978845608028654f * (v + 0.044715f * v * v * v);
    u = fminf(fmaxf(u, -30.f), 30.f);
    float e = __expf(u);
    return 0.5f * v * (1.f + (e - 1.f) / (e + 1.f));
}

// ---------------- prep: 4 weight convert+transposes AND ln1 in ONE kernel
__global__ __launch_bounds__(256)
void prep_all(const float* __restrict__ w_attn, const float* __restrict__ w_proj,
              const float* __restrict__ w_fc,   const float* __restrict__ w_fc2,
              unsigned short* __restrict__ wattnT, unsigned short* __restrict__ wprojT,
              unsigned short* __restrict__ wfcT,   unsigned short* __restrict__ wfc2T,
              const float* __restrict__ x, const float* __restrict__ ln1_g,
              const float* __restrict__ ln1_b, unsigned short* __restrict__ xn1){
    const int bid = blockIdx.x;
    const int t = threadIdx.x;
    if (bid >= 12288){
        const int row = bid - 12288;
        const float4* xr = (const float4*)(x + (size_t)row * TC);
        float4 v = xr[t];
        float s  = v.x + v.y + v.z + v.w;
        float s2 = v.x*v.x + v.y*v.y + v.z*v.z + v.w*v.w;
        #pragma unroll
        for (int off = 32; off; off >>= 1){
            s  += __shfl_down(s,  off);
            s2 += __shfl_down(s2, off);
        }
        __shared__ float red[8];
        int l = t & 63, wv = t >> 6;
        if (l == 0){ red[wv] = s; red[4 + wv] = s2; }
        __syncthreads();
        float S  = red[0] + red[1] + red[2] + red[3];
        float S2 = red[4] + red[5] + red[6] + red[7];
        float mu = S * (1.f / TC);
        float var = S2 * (1.f / TC) - mu * mu;
        float rs = rsqrtf(var + 1e-5f);
        int c = t * 4;
        float4 gg = *(const float4*)(ln1_g + c);
        float4 bb = *(const float4*)(ln1_b + c);
        u16x4 o;
        o[0] = f2bf((v.x - mu) * rs * gg.x + bb.x);
        o[1] = f2bf((v.y - mu) * rs * gg.y + bb.y);
        o[2] = f2bf((v.z - mu) * rs * gg.z + bb.z);
        o[3] = f2bf((v.w - mu) * rs * gg.w + bb.w);
        *(u16x4*)(xn1 + (size_t)row * TC + c) = o;
        return;
    }
    __shared__ float tile[32][33];
    const float* in; unsigned short* out; int K, N, bx, by;
    if (bid < 3072)      { in=w_attn; out=wattnT; K=1024; N=3072; bx=bid%96;  by=bid/96; }
    else if (bid < 4096) { int lo=bid-3072; in=w_proj; out=wprojT; K=1024; N=1024; bx=lo%32;  by=lo/32; }
    else if (bid < 8192) { int lo=bid-4096; in=w_fc;   out=wfcT;   K=1024; N=4096; bx=lo%128; by=lo/128; }
    else                 { int lo=bid-8192; in=w_fc2;  out=wfc2T;  K=4096; N=1024; bx=lo%32;  by=lo/32; }
    int tx = t & 31, ty = t >> 5;
    int n0 = bx * 32, k0 = by * 32;
    #pragma unroll
    for (int i = 0; i < 4; i++)
        tile[ty + 8*i][tx] = in[(size_t)(k0 + ty + 8*i) * N + n0 + tx];
    __syncthreads();
    #pragma unroll
    for (int i = 0; i < 4; i++)
        out[(size_t)(n0 + ty + 8*i) * K + k0 + tx] = f2bf(tile[tx][ty + 8*i]);
}

// ---------------- layernorm (ln2): x f32 [.][1024] -> y bf16
__global__ __launch_bounds__(256)
void ln_kernel(const float* __restrict__ x, const float* __restrict__ g,
               const float* __restrict__ be, unsigned short* __restrict__ y){
    const int row = blockIdx.x, t = threadIdx.x;
    const float4* xr = (const float4*)(x + (size_t)row * TC);
    float4 v = xr[t];
    float s  = v.x + v.y + v.z + v.w;
    float s2 = v.x*v.x + v.y*v.y + v.z*v.z + v.w*v.w;
    #pragma unroll
    for (int off = 32; off; off >>= 1){
        s  += __shfl_down(s,  off);
        s2 += __shfl_down(s2, off);
    }
    __shared__ float red[8];
    int l = t & 63, wv = t >> 6;
    if (l == 0){ red[wv] = s; red[4 + wv] = s2; }
    __syncthreads();
    float S  = red[0] + red[1] + red[2] + red[3];
    float S2 = red[4] + red[5] + red[6] + red[7];
    float mu = S * (1.f / TC);
    float var = S2 * (1.f / TC) - mu * mu;
    float rs = rsqrtf(var + 1e-5f);
    int c = t * 4;
    float4 gg = *(const float4*)(g + c);
    float4 bb = *(const float4*)(be + c);
    u16x4 o;
    o[0] = f2bf((v.x - mu) * rs * gg.x + bb.x);
    o[1] = f2bf((v.y - mu) * rs * gg.y + bb.y);
    o[2] = f2bf((v.z - mu) * rs * gg.z + bb.z);
    o[3] = f2bf((v.w - mu) * rs * gg.w + bb.w);
    *(u16x4*)(y + (size_t)row * TC + c) = o;
}

// ---------------- 128x128 GEMM (m97 structure) + XCD swizzle
// EPI 0: +bias->bf16 ; 1: +bias+resid->f32 ; 2: +bias,gelu->bf16
template<int EPI>
__global__ __launch_bounds__(256, 2)
void gemm_bt(const unsigned short* __restrict__ A,
             const unsigned short* __restrict__ Bt,
             const float* __restrict__ bias,
             const float* __restrict__ resid,
             void* __restrict__ outv,
             int M, int N, int K){
    __shared__ unsigned short lA[128 * 32];
    __shared__ unsigned short lB[128 * 32];
    const int t = threadIdx.x, w = t >> 6, l = t & 63, lr = l & 15, lg = l >> 4;
    const int nt = N >> 7;
    const int nwg = gridDim.x;
    const int bid = blockIdx.x;
    int wg = (nwg & 7) ? bid : ((bid & 7) * (nwg >> 3) + (bid >> 3));
    const int bm = wg / nt, bn = wg % nt;
    const int row0 = bm << 7, col0 = bn << 7;
    const int wr = w >> 1, wc = w & 1;

    f32x4 acc[4][4];
    #pragma unroll
    for (int i = 0; i < 4; i++)
        #pragma unroll
        for (int j = 0; j < 4; j++) acc[i][j] = (f32x4){0.f,0.f,0.f,0.f};

    const char* Ag = (const char*)(A + (size_t)(row0 + (t >> 2)) * K) + (t & 3) * 16;
    const char* Bg = (const char*)(Bt + (size_t)(col0 + (t >> 2)) * K) + (t & 3) * 16;
    const size_t rstep = (size_t)64 * K * 2;
    char* lAw = (char*)lA + w * 1024;
    char* lBw = (char*)lB + w * 1024;

    for (int k0 = 0; k0 < K; k0 += 32){
        size_t kb = (size_t)k0 * 2;
        gl_lds16(Ag + kb,          lAw);
        gl_lds16(Ag + kb + rstep,  lAw + 4096);
        gl_lds16(Bg + kb,          lBw);
        gl_lds16(Bg + kb + rstep,  lBw + 4096);
        __syncthreads();
        bf16x8 af[4], bfr[4];
        #pragma unroll
        for (int mi = 0; mi < 4; mi++)
            af[mi] = ldbf8(lA + (wr*64 + mi*16 + lr) * 32 + lg * 8);
        #pragma unroll
        for (int ni = 0; ni < 4; ni++)
            bfr[ni] = ldbf8(lB + (wc*64 + ni*16 + lr) * 32 + lg * 8);
        #pragma unroll
        for (int mi = 0; mi < 4; mi++)
            #pragma unroll
            for (int ni = 0; ni < 4; ni++)
                acc[mi][ni] = __builtin_amdgcn_mfma_f32_16x16x32_bf16(
                    af[mi], bfr[ni], acc[mi][ni], 0, 0, 0);
        __syncthreads();
    }

    float bcol[4];
    #pragma unroll
    for (int ni = 0; ni < 4; ni++) bcol[ni] = bias[col0 + wc*64 + ni*16 + lr];
    #pragma unroll
    for (int mi = 0; mi < 4; mi++){
        #pragma unroll
        for (int j = 0; j < 4; j++){
            int row = row0 + wr*64 + mi*16 + lg*4 + j;
            size_t base = (size_t)row * N + col0 + wc*64 + lr;
            #pragma unroll
            for (int ni = 0; ni < 4; ni++){
                float v = acc[mi][ni][j] + bcol[ni];
                size_t idx = base + (size_t)ni * 16;
                if (EPI == 0)      ((unsigned short*)outv)[idx] =
                    __builtin_bit_cast(unsigned short, (__bf16)v);
                else if (EPI == 1) ((float*)outv)[idx] = v + resid[idx];
                else               ((unsigned short*)outv)[idx] =
                    __builtin_bit_cast(unsigned short, (__bf16)gelu_tanh(v));
            }
        }
    }
}

// ---------------- 256x256 GEMM pieces
template<int MH>
__device__ __forceinline__ void gloadA(const unsigned short* bufA, bf16x8 (&af)[4][2],
                                       int wm, int lr, int sl0, int sl1){
    #pragma unroll
    for (int i = 0; i < 4; i++){
        int lrow = (wm*128 + (MH*4 + i)*16 + lr) * 64;
        af[i][0] = ldbf8(bufA + lrow + sl0);
        af[i][1] = ldbf8(bufA + lrow + sl1);
    }
}
__device__ __forceinline__ void gloadB(const unsigned short* bufB, bf16x8 (&bfr)[4][2],
                                       int wn, int lr, int sl0, int sl1){
    #pragma unroll
    for (int i = 0; i < 4; i++){
        int brow = (wn*64 + i*16 + lr) * 64;
        bfr[i][0] = ldbf8(bufB + brow + sl0);
        bfr[i][1] = ldbf8(bufB + brow + sl1);
    }
}
template<int MH, int NH>
__device__ __forceinline__ void gmma(const bf16x8 (&af)[4][2], const bf16x8 (&bfr)[4][2],
                                     f32x4 (&acc)[8][4]){
    #pragma unroll
    for (int i = 0; i < 4; i++)
        #pragma unroll
        for (int j = 0; j < 2; j++){
            f32x4& a = acc[MH*4 + i][NH*2 + j];
            a = __builtin_amdgcn_mfma_f32_16x16x32_bf16(af[i][0], bfr[NH*2+j][0], a, 0,0,0);
            a = __builtin_amdgcn_mfma_f32_16x16x32_bf16(af[i][1], bfr[NH*2+j][1], a, 0,0,0);
        }
}

// 256x256 K-loop: 2 barriers/tile, reads+MFMA free-scheduled (compiler lgkmcnt),
// double-buffered with counted vmcnt(2).
#define G256_LOOP(NT_, KBEG_)                                                   \
    for (int tk = 0; tk < (NT_); ++tk){                                         \
        const int cur = tk & 1;                                                 \
        const bool more1 = (tk + 1) < (NT_);                                    \
        const bool more2 = (tk + 2) < (NT_);                                    \
        const unsigned short* bufA = &lds[cur][0][0];                           \
        const unsigned short* bufB = &lds[cur][1][0];                           \
        if (more1) asm volatile("s_waitcnt vmcnt(2)" ::: "memory");             \
        else       asm volatile("s_waitcnt vmcnt(0)" ::: "memory");             \
        __builtin_amdgcn_s_barrier();                                           \
        {                                                                       \
            bf16x8 afr[4][2], bfr[4][2];                                        \
            gloadA<0>(bufA, afr, wm, lr, sl0, sl1);                             \
            gloadB(bufB, bfr, wn, lr, sl0, sl1);                                \
            if (more1){                                                         \
                stage(cur ^ 1, (KBEG_) + (tk + 1)*64, 1);                       \
                stage(cur ^ 1, (KBEG_) + (tk + 1)*64, 2);                       \
            }                                                                   \
            __builtin_amdgcn_s_setprio(1);                                      \
            gmma<0,0>(afr, bfr, acc);                                           \
            gmma<0,1>(afr, bfr, acc);                                           \
            __builtin_amdgcn_s_setprio(0);                                      \
            gloadA<1>(bufA, afr, wm, lr, sl0, sl1);                             \
            if (more1) stage(cur ^ 1, (KBEG_) + (tk + 1)*64, 3);                \
            __builtin_amdgcn_s_setprio(1);                                      \
            gmma<1,0>(afr, bfr, acc);                                           \
            gmma<1,1>(afr, bfr, acc);                                           \
            __builtin_amdgcn_s_setprio(0);                                      \
        }                                                                       \
        __builtin_amdgcn_s_barrier();                                           \
        if (more2) stage(cur, (KBEG_) + (tk + 2)*64, 0);                        \
    }

template<int EPI>  // 0: +bias->bf16 ; 2: +bias,gelu->bf16
__global__ __launch_bounds__(512, 1)
void gemm256(const unsigned short* __restrict__ A,
             const unsigned short* __restrict__ Bt,
             const float* __restrict__ bias,
             void* __restrict__ outv,
             int M, int N, int K){
    __shared__ unsigned short lds[2][2][256*64];
    const int t = threadIdx.x;
    const int w = t >> 6, l = t & 63, lr = l & 15, lg = l >> 4;
    const int wm = w >> 2, wn = w & 3;
    const int lr7 = lr & 7;
    const int sl0 = (lg ^ lr7) << 3;
    const int sl1 = ((4 + lg) ^ lr7) << 3;
    const int nbn = N >> 8;
    const int nwg = (M >> 8) * nbn;
    const int bid = blockIdx.x;
    const int wg = (nwg & 7) ? bid : ((bid & 7) * (nwg >> 3) + (bid >> 3));
    const int bm = wg / nbn, bn = wg % nbn;
    const size_t row0 = (size_t)bm << 8, col0 = (size_t)bn << 8;
    const int NT = K >> 6;

    f32x4 acc[8][4];
    #pragma unroll
    for (int i = 0; i < 8; i++)
        #pragma unroll
        for (int j = 0; j < 4; j++) acc[i][j] = (f32x4){0.f,0.f,0.f,0.f};

    int rowc[4], slogc[4];
    #pragma unroll
    for (int c = 0; c < 4; c++){
        int seg = t + (c << 9);
        rowc[c]  = seg >> 3;
        slogc[c] = (((seg & 7) ^ ((seg >> 3) & 7)) << 3);
    }
    const unsigned short* Abase = A  + row0 * K;
    const unsigned short* Bbase = Bt + col0 * K;
    auto stage = [&](int buf, int kofs, int c){
        int seg = t + (c << 9);
        const unsigned short* sa = Abase + (size_t)rowc[c] * K + kofs + slogc[c];
        const unsigned short* sb = Bbase + (size_t)rowc[c] * K + kofs + slogc[c];
        gl_lds16(sa, (void*)&lds[buf][0][seg * 8]);
        gl_lds16(sb, (void*)&lds[buf][1][seg * 8]);
    };

    #pragma unroll
    for (int c = 0; c < 4; c++) stage(0, 0, c);
    if (NT > 1) stage(1, 64, 0);

    G256_LOOP(NT, 0)

    float bcol[4];
    #pragma unroll
    for (int ni = 0; ni < 4; ni++) bcol[ni] = bias[col0 + wn*64 + ni*16 + lr];
    unsigned short* outp = (unsigned short*)outv;
    #pragma unroll
    for (int mi = 0; mi < 8; mi++){
        #pragma unroll
        for (int j = 0; j < 4; j++){
            size_t row = row0 + wm*128 + mi*16 + lg*4 + j;
            size_t base = row * N + col0 + wn*64 + lr;
            #pragma unroll
            for (int ni = 0; ni < 4; ni++){
                float v = acc[mi][ni][j] + bcol[ni];
                size_t idx = base + (size_t)ni * 16;
                if (EPI == 0) outp[idx] = __builtin_bit_cast(unsigned short, (__bf16)v);
                else          outp[idx] = __builtin_bit_cast(unsigned short, (__bf16)gelu_tanh(v));
            }
        }
    }
}

// ---------------- 256x256 split-K GEMM: grid = SK*(M/256)*(N/256); bf16 partials
__global__ __launch_bounds__(512, 1)
void gemm256sk(const unsigned short* __restrict__ A,
               const unsigned short* __restrict__ Bt,
               unsigned short* __restrict__ pout,
               int M, int N, int K, int klen){
    __shared__ unsigned short lds[2][2][256*64];
    const int t = threadIdx.x;
    const int w = t >> 6, l = t & 63, lr = l & 15, lg = l >> 4;
    const int wm = w >> 2, wn = w & 3;
    const int lr7 = lr & 7;
    const int sl0 = (lg ^ lr7) << 3;
    const int sl1 = ((4 + lg) ^ lr7) << 3;
    const int nbn = N >> 8;
    const int ntile = (M >> 8) * nbn;
    const int nwg = gridDim.x;
    const int bid = blockIdx.x;
    int wg = (nwg & 7) ? bid : ((bid & 7) * (nwg >> 3) + (bid >> 3));
    const int kh = wg / ntile;
    wg -= kh * ntile;
    const int bm = wg / nbn, bn = wg % nbn;
    const size_t row0 = (size_t)bm << 8, col0 = (size_t)bn << 8;
    const int NT = klen >> 6;
    const int kbeg = kh * klen;

    f32x4 acc[8][4];
    #pragma unroll
    for (int i = 0; i < 8; i++)
        #pragma unroll
        for (int j = 0; j < 4; j++) acc[i][j] = (f32x4){0.f,0.f,0.f,0.f};

    int rowc[4], slogc[4];
    #pragma unroll
    for (int c = 0; c < 4; c++){
        int seg = t + (c << 9);
        rowc[c]  = seg >> 3;
        slogc[c] = (((seg & 7) ^ ((seg >> 3) & 7)) << 3);
    }
    const unsigned short* Abase = A  + row0 * K;
    const unsigned short* Bbase = Bt + col0 * K;
    auto stage = [&](int buf, int kofs, int c){
        int seg = t + (c << 9);
        const unsigned short* sa = Abase + (size_t)rowc[c] * K + kofs + slogc[c];
        const unsigned short* sb = Bbase + (size_t)rowc[c] * K + kofs + slogc[c];
        gl_lds16(sa, (void*)&lds[buf][0][seg * 8]);
        gl_lds16(sb, (void*)&lds[buf][1][seg * 8]);
    };

    #pragma unroll
    for (int c = 0; c < 4; c++) stage(0, kbeg, c);
    if (NT > 1) stage(1, kbeg + 64, 0);

    G256_LOOP(NT, kbeg)

    unsigned short* outp = pout + (size_t)kh * M * N;
    #pragma unroll
    for (int mi = 0; mi < 8; mi++){
        #pragma unroll
        for (int j = 0; j < 4; j++){
            size_t row = row0 + wm*128 + mi*16 + lg*4 + j;
            size_t base = row * N + col0 + wn*64 + lr;
            #pragma unroll
            for (int ni = 0; ni < 4; ni++)
                outp[base + (size_t)ni * 16] =
                    __builtin_bit_cast(unsigned short, (__bf16)acc[mi][ni][j]);
        }
    }
}

// ---------------- split-K x4 combine: out = sum(p[0..3]) + bias + resid (f32)
__global__ __launch_bounds__(256)
void combine_k4(const unsigned short* __restrict__ p,
                const float* __restrict__ bias, const float* __restrict__ resid,
                float* __restrict__ out){
    const size_t PS = (size_t)TM * TC;
    const int total = TM * TC / 4;
    for (int i = blockIdx.x * 256 + threadIdx.x; i < total; i += gridDim.x * 256){
        int e = i * 4;
        u16x4 a0 = *(const u16x4*)(p + e);
        u16x4 a1 = *(const u16x4*)(p + PS + e);
        u16x4 a2 = *(const u16x4*)(p + 2*PS + e);
        u16x4 a3 = *(const u16x4*)(p + 3*PS + e);
        float4 r = *(const float4*)(resid + e);
        float4 bb = *(const float4*)(bias + (e & (TC - 1)));
        float4 o;
        o.x = bf2f(a0[0]) + bf2f(a1[0]) + bf2f(a2[0]) + bf2f(a3[0]) + r.x + bb.x;
        o.y = bf2f(a0[1]) + bf2f(a1[1]) + bf2f(a2[1]) + bf2f(a3[1]) + r.y + bb.y;
        o.z = bf2f(a0[2]) + bf2f(a1[2]) + bf2f(a2[2]) + bf2f(a3[2]) + r.z + bb.z;
        o.w = bf2f(a0[3]) + bf2f(a1[3]) + bf2f(a2[3]) + bf2f(a3[3]) + r.w + bb.w;
        *(float4*)(out + e) = o;
    }
}

// ---------------- V pre-transpose: qkv [tok][3C] -> vTg [bh][kt][64 d][80]
__global__ __launch_bounds__(256)
void vtrans(const unsigned short* __restrict__ qkv, unsigned short* __restrict__ vTg){
    __shared__ unsigned short lt[64][68];
    int kt = blockIdx.x & (NQT - 1);
    int bh = blockIdx.x >> 5;
    int h = bh & (TH - 1), b = bh >> 4;
    int t = threadIdx.x;
    int r = t >> 2, c4 = t & 3;
    const unsigned short* src = qkv + (size_t)(b*TT + kt*64 + r) * (3*TC) + 2*TC + h*THD;
    u16x8 a0 = *(const u16x8*)(src + c4*8);
    u16x8 a1 = *(const u16x8*)(src + 32 + c4*8);
    #pragma unroll
    for (int j = 0; j < 8; j++){
        lt[r][c4*8 + j]      = a0[j];
        lt[r][32 + c4*8 + j] = a1[j];
    }
    __syncthreads();
    int d = t >> 2;
    unsigned short* dst = vTg + ((size_t)bh * NQT + kt) * (64*80) + (size_t)d * 80;
    u16x8 o0, o1;
    #pragma unroll
    for (int j = 0; j < 8; j++){
        o0[j] = lt[c4*8 + j][d];
        o1[j] = lt[32 + c4*8 + j][d];
    }
    *(u16x8*)(dst + c4*8)      = o0;
    *(u16x8*)(dst + 32 + c4*8) = o1;
}

// ---------------- flash attention (causal): 1024 blocks (bh x 32 q-tiles of 64 rows),
// 4 waves x 16 q-rows; KVBLK=128 staged to LDS; SWAPPED QK^T (mfma(K,Q) -> S^T);
// native bf16 cvt_pk for P-pack; P stride 144 (read conflicts 4-way)
__global__ __launch_bounds__(256, 3)
void attn_kernel(const unsigned short* __restrict__ qkv,
                 const unsigned short* __restrict__ vTg,
                 unsigned short* __restrict__ attn_out){
    __shared__ unsigned short kbuf[128*64];   // 16 KB (2 kv tiles)
    __shared__ unsigned short vbuf[128*64];   // 16 KB (2 V^T tiles)
    __shared__ unsigned short pl[4][16*144];  // 18.4 KB  (total ~50.4 KB -> 3/CU)

    const int bid = blockIdx.x;
    const int qrank = bid >> 5;          // 0..31, 0 = longest
    const int bh = bid & 31;
    const int h = bh & (TH - 1), b = bh >> 4;
    const int qb = 31 - qrank;           // q-tile (64 rows)
    const int q0 = qb << 6;
    const int t = threadIdx.x, w = t >> 6, l = t & 63, lr = l & 15, lg = l >> 4;
    const int lr7 = lr & 7;
    const int sl0 = (lg ^ lr7) << 3;
    const int sl1 = ((4 + lg) ^ lr7) << 3;
    const float SC = 0.18033688011112042f;   // 0.125 * log2(e)

    const int NP = (qb >> 1) + 1;            // kv pairs
    const int qrow_base = q0 + w*16;
    const int myq = qrow_base + lr;          // this thread's q-row (softmax state owner)

    // staging: 4 virtual 256-thread passes per operand; dest = vt*16B (lane-contig)
    const unsigned short* kgp[4];
    const unsigned short* vgp[4];
    #pragma unroll
    for (int p = 0; p < 4; p++){
        int vt = p*256 + t;
        int r  = vt >> 3;
        int sc = ((vt & 7) ^ (r & 7)) * 8;
        kgp[p] = qkv + (size_t)(b*TT + r) * (3*TC) + TC + h*THD + sc;
        vgp[p] = vTg + (size_t)bh * (NQT*64*80)
               + (size_t)(r >> 6) * (64*80) + (size_t)(r & 63) * 80 + sc;
    }
    const size_t kstep2 = (size_t)128 * (3*TC);   // 2 token-tiles
    const size_t vstep2 = (size_t)2 * (64*80);

    auto stage = [&](int pi){
        #pragma unroll
        for (int p = 0; p < 4; p++)
            gl_lds16(kgp[p] + (size_t)pi*kstep2, (void*)&kbuf[(p*256 + t)*8]);
        #pragma unroll
        for (int p = 0; p < 4; p++)
            gl_lds16(vgp[p] + (size_t)pi*vstep2, (void*)&vbuf[(p*256 + t)*8]);
    };

    const unsigned short* qr =
        qkv + (size_t)(b*TT + myq) * (3*TC) + h*THD;
    bf16x8 q0f = ldbf8(qr + lg*8), q1f = ldbf8(qr + 32 + lg*8);

    bf16x8 ones;
    #pragma unroll
    for (int i = 0; i < 8; i++) ones[i] = (__bf16)1.0f;

    f32x4 o[5];
    float m = -1e30f;   // running max (scaled/log2 domain) for q-row `myq`
    #pragma unroll
    for (int i = 0; i < 5; i++) o[i] = (f32x4){0.f,0.f,0.f,0.f};

    unsigned short* plw = &pl[w][0];

    stage(0);
    for (int pi = 0; pi < NP; ++pi){
        const int t0 = 2*pi, t1 = 2*pi + 1;
        asm volatile("s_waitcnt vmcnt(0)" ::: "memory");
        __builtin_amdgcn_s_barrier();

        // ---- S^T = K Q^T over 128 kv: s[cb][j] = S[kv = cb*16+lg*4+j][q = lr] ----
        f32x4 s[8];
        __builtin_amdgcn_s_setprio(1);
        #pragma unroll
        for (int cb = 0; cb < 8; cb++){
            bf16x8 ka = ldbf8(kbuf + (cb*16 + lr)*64 + sl0);
            bf16x8 kbf = ldbf8(kbuf + (cb*16 + lr)*64 + sl1);
            f32x4 z = (f32x4){0.f,0.f,0.f,0.f};
            z = __builtin_amdgcn_mfma_f32_16x16x32_bf16(ka, q0f, z, 0,0,0);
            z = __builtin_amdgcn_mfma_f32_16x16x32_bf16(kbf, q1f, z, 0,0,0);
            s[cb] = z;
        }
        __builtin_amdgcn_s_setprio(0);
        // ---- causal masks: kv_global = tile*64 + cb*16 + lg*4 + j vs q = myq ----
        if (t0 == qb){
            #pragma unroll
            for (int cb = 0; cb < 4; cb++)
                #pragma unroll
                for (int j = 0; j < 4; j++)
                    if (t0*64 + cb*16 + lg*4 + j > myq) s[cb][j] = -1e30f;
        }
        if (t1 == qb){
            #pragma unroll
            for (int cb = 4; cb < 8; cb++)
                #pragma unroll
                for (int j = 0; j < 4; j++)
                    if (t1*64 + (cb-4)*16 + lg*4 + j > myq) s[cb][j] = -1e30f;
        } else if (t1 > qb){
            #pragma unroll
            for (int cb = 4; cb < 8; cb++)
                #pragma unroll
                for (int j = 0; j < 4; j++) s[cb][j] = -1e30f;
        }
        // ---- row max: local 32-chain + 2-step cross-lane (lanes sharing lr) ----
        float mloc = s[0][0];
        #pragma unroll
        for (int cb = 0; cb < 8; cb++)
            #pragma unroll
            for (int j = 0; j < 4; j++) mloc = fmaxf(mloc, s[cb][j]);
        mloc = fmaxf(mloc, __shfl_xor(mloc, 16));
        mloc = fmaxf(mloc, __shfl_xor(mloc, 32));
        // ---- defer-max rescale (exact skip) ----
        bool grow = (mloc * SC > m);
        float al = 1.f;
        if (__any(grow)){
            float mn = fmaxf(m, mloc * SC);
            al = exp2f(m - mn);
            m = mn;
            float alb[4];
            #pragma unroll
            for (int j = 0; j < 4; j++) alb[j] = __shfl(al, lg*4 + j);
            #pragma unroll
            for (int db = 0; db < 5; db++)
                #pragma unroll
                for (int j = 0; j < 4; j++) o[db][j] *= alb[j];
        }
        // ---- P = exp2(s*SC - m), native bf16 casts (cvt_pk), packed b64 writes ----
        #pragma unroll
        for (int cb = 0; cb < 8; cb++){
            u16x4 pk;
            #pragma unroll
            for (int j = 0; j < 4; j++){
                float e = exp2f(__builtin_fmaf(s[cb][j], SC, -m));
                pk[j] = __builtin_bit_cast(unsigned short, (__bf16)e);
            }
            *(u16x4*)(plw + lr*144 + cb*16 + lg*4) = pk;
        }
        // ---- PV over both kv tiles ----
        bf16x8 pa0 = ldbf8(plw + lr*144 + lg*8);
        bf16x8 pa1 = ldbf8(plw + lr*144 + 32 + lg*8);
        bf16x8 pa2 = ldbf8(plw + lr*144 + 64 + lg*8);
        bf16x8 pa3 = ldbf8(plw + lr*144 + 96 + lg*8);
        __builtin_amdgcn_s_setprio(1);
        #pragma unroll
        for (int db = 0; db < 4; db++){
            bf16x8 v0a = ldbf8(vbuf + (db*16 + lr)*64 + sl0);
            bf16x8 v0b = ldbf8(vbuf + (db*16 + lr)*64 + sl1);
            o[db] = __builtin_amdgcn_mfma_f32_16x16x32_bf16(pa0, v0a, o[db], 0,0,0);
            o[db] = __builtin_amdgcn_mfma_f32_16x16x32_bf16(pa1, v0b, o[db], 0,0,0);
            bf16x8 v1a = ldbf8(vbuf + (64 + db*16 + lr)*64 + sl0);
            bf16x8 v1b = ldbf8(vbuf + (64 + db*16 + lr)*64 + sl1);
            o[db] = __builtin_amdgcn_mfma_f32_16x16x32_bf16(pa2, v1a, o[db], 0,0,0);
            o[db] = __builtin_amdgcn_mfma_f32_16x16x32_bf16(pa3, v1b, o[db], 0,0,0);
        }
        o[4] = __builtin_amdgcn_mfma_f32_16x16x32_bf16(pa0, ones, o[4], 0,0,0);
        o[4] = __builtin_amdgcn_mfma_f32_16x16x32_bf16(pa1, ones, o[4], 0,0,0);
        o[4] = __builtin_amdgcn_mfma_f32_16x16x32_bf16(pa2, ones, o[4], 0,0,0);
        o[4] = __builtin_amdgcn_mfma_f32_16x16x32_bf16(pa3, ones, o[4], 0,0,0);
        __builtin_amdgcn_s_setprio(0);

        __builtin_amdgcn_s_barrier();   // all reads done -> safe to overwrite buffers
        if (pi + 1 < NP) stage(pi + 1);
    }

    __bf16* aout = (__bf16*)attn_out;
    #pragma unroll
    for (int j = 0; j < 4; j++){
        float inv = 1.f / o[4][j];
        size_t tok = (size_t)(b*TT + qrow_base + lg*4 + j);
        #pragma unroll
        for (int db = 0; db < 4; db++)
            aout[tok*TC + h*THD + db*16 + lr] = (__bf16)(o[db][j] * inv);
    }
}

extern "C" void kernel_launch(void* const* d_in, const int* in_sizes, int n_in,
                              void* d_out, int out_size, void* d_ws, size_t ws_size,
                              hipStream_t stream){
    const float* x      = (const float*)d_in[0];
    const float* ln1_g  = (const float*)d_in[1];
    const float* ln1_b  = (const float*)d_in[2];
    const float* w_attn = (const float*)d_in[3];
    const float* b_attn = (const float*)d_in[4];
    const float* w_proj = (const float*)d_in[5];
    const float* b_proj = (const float*)d_in[6];
    const float* ln2_g  = (const float*)d_in[7];
    const float* ln2_b  = (const float*)d_in[8];
    const float* w_fc   = (const float*)d_in[9];
    const float* b_fc   = (const float*)d_in[10];
    const float* w_fc2  = (const float*)d_in[11];
    const float* b_fc2  = (const float*)d_in[12];
    float* out = (float*)d_out;

    char* ws = (char*)d_ws;
    size_t off = 0;
    auto alloc = [&](size_t bytes) -> void* {
        void* p = ws + off;
        off += (bytes + 255) & ~(size_t)255;
        return p;
    };
    unsigned short* wattnT = (unsigned short*)alloc((size_t)3072*1024*2);
    unsigned short* wprojT = (unsigned short*)alloc((size_t)1024*1024*2);
    unsigned short* wfcT   = (unsigned short*)alloc((size_t)4096*1024*2);
    unsigned short* wfc2T  = (unsigned short*)alloc((size_t)1024*4096*2);
    unsigned short* xn1    = (unsigned short*)alloc((size_t)TM*TC*2);    // + qkvb = split-K partial arena
    unsigned short* qkvb   = (unsigned short*)alloc((size_t)TM*3*TC*2);
    float*          resid1 = (float*)alloc((size_t)TM*TC*4);
    unsigned short* xn2    = (unsigned short*)alloc((size_t)TM*TC*2);
    unsigned short* hbuf   = (unsigned short*)alloc((size_t)TM*4*TC*2);
    unsigned short* attnO  = (unsigned short*)alloc((size_t)TM*TC*2);
    unsigned short* vTg    = (unsigned short*)alloc((size_t)TB*TH*NQT*64*80*2);

    unsigned short* pks = xn1;   // 4 x TM*TC bf16 = exactly xn1+qkvb (dead after attn)

    prep_all<<<12288 + TM, 256, 0, stream>>>(
        w_attn, w_proj, w_fc, w_fc2, wattnT, wprojT, wfcT, wfc2T,
        x, ln1_g, ln1_b, xn1);

    gemm256<0><<<(TM/256)*(3072/256), 512, 0, stream>>>(
        xn1, wattnT, b_attn, qkvb, TM, 3072, 1024);

    vtrans<<<TB*TH*NQT, 256, 0, stream>>>(qkvb, vTg);

    attn_kernel<<<TB*TH*NQT, 256, 0, stream>>>(qkvb, vTg, attnO);

    gemm_bt<1><<<(TM/128)*(1024/128), 256, 0, stream>>>(
        attnO, wprojT, b_proj, x, resid1, TM, 1024, 1024);

    ln_kernel<<<TM, 256, 0, stream>>>(resid1, ln2_g, ln2_b, xn2);

    gemm256<2><<<(TM/256)*(4096/256), 512, 0, stream>>>(
        xn2, wfcT, b_fc, hbuf, TM, 4096, 1024);

    // FC2: 256x256 split-K x4 (256 blocks = 1/CU), bf16 partials, then combine
    gemm256sk<<<4*(TM/256)*(1024/256), 512, 0, stream>>>(
        hbuf, wfc2T, pks, TM, 1024, 4096, 1024);
    combine_k4<<<2048, 256, 0, stream>>>(pks, b_fc2, resid1, out);
}

// Round 24
// 211.578 us; speedup vs baseline: 1.0168x; 1.0103x over previous
//
#include <hip/hip_runtime.h>
#include <math.h>

#define TB 2
#define TT 2048
#define TC 1024
#define TH 16
#define THD 64
#define TM (TB*TT)   // 4096 tokens
#define NQT 32       // TT/64 kv tiles

typedef __bf16 bf16x8 __attribute__((ext_vector_type(8)));
typedef float f32x4 __attribute__((ext_vector_type(4)));
typedef unsigned short u16x8 __attribute__((ext_vector_type(8)));
typedef unsigned short u16x4 __attribute__((ext_vector_type(4)));

__device__ __forceinline__ unsigned short f2bf(float f){
    unsigned int u = __builtin_bit_cast(unsigned int, f);
    u = (u + 0x7FFFu + ((u >> 16) & 1u)) >> 16;
    return (unsigned short)u;
}
__device__ __forceinline__ float bf2f(unsigned short h){
    unsigned int u = ((unsigned int)h) << 16;
    return __builtin_bit_cast(float, u);
}
__device__ __forceinline__ bf16x8 ldbf8(const unsigned short* p){
    return __builtin_bit_cast(bf16x8, *(const u16x8*)p);
}
__device__ __forceinline__ void gl_lds16(const void* g, void* l){
    __builtin_amdgcn_global_load_lds(
        (const __attribute__((address_space(1))) unsigned int*)g,
        (__attribute__((address_space(3))) unsigned int*)l,
        16, 0, 0);
}
__device__ __forceinline__ float gelu_tanh(float v){
    float u = 2.0f * 0.7978845608028654f * (v + 0.044715f * v * v * v);
    u = fminf(fmaxf(u, -30.f), 30.f);
    float e = __expf(u);
    return 0.5f * v * (1.f + (e - 1.f) / (e + 1.f));
}

// ---------------- prep: 4 weight convert+transposes AND ln1 in ONE kernel
__global__ __launch_bounds__(256)
void prep_all(const float* __restrict__ w_attn, const float* __restrict__ w_proj,
              const float* __restrict__ w_fc,   const float* __restrict__ w_fc2,
              unsigned short* __restrict__ wattnT, unsigned short* __restrict__ wprojT,
              unsigned short* __restrict__ wfcT,   unsigned short* __restrict__ wfc2T,
              const float* __restrict__ x, const float* __restrict__ ln1_g,
              const float* __restrict__ ln1_b, unsigned short* __restrict__ xn1){
    const int bid = blockIdx.x;
    const int t = threadIdx.x;
    if (bid >= 12288){
        const int row = bid - 12288;
        const float4* xr = (const float4*)(x + (size_t)row * TC);
        float4 v = xr[t];
        float s  = v.x + v.y + v.z + v.w;
        float s2 = v.x*v.x + v.y*v.y + v.z*v.z + v.w*v.w;
        #pragma unroll
        for (int off = 32; off; off >>= 1){
            s  += __shfl_down(s,  off);
            s2 += __shfl_down(s2, off);
        }
        __shared__ float red[8];
        int l = t & 63, wv = t >> 6;
        if (l == 0){ red[wv] = s; red[4 + wv] = s2; }
        __syncthreads();
        float S  = red[0] + red[1] + red[2] + red[3];
        float S2 = red[4] + red[5] + red[6] + red[7];
        float mu = S * (1.f / TC);
        float var = S2 * (1.f / TC) - mu * mu;
        float rs = rsqrtf(var + 1e-5f);
        int c = t * 4;
        float4 gg = *(const float4*)(ln1_g + c);
        float4 bb = *(const float4*)(ln1_b + c);
        u16x4 o;
        o[0] = f2bf((v.x - mu) * rs * gg.x + bb.x);
        o[1] = f2bf((v.y - mu) * rs * gg.y + bb.y);
        o[2] = f2bf((v.z - mu) * rs * gg.z + bb.z);
        o[3] = f2bf((v.w - mu) * rs * gg.w + bb.w);
        *(u16x4*)(xn1 + (size_t)row * TC + c) = o;
        return;
    }
    __shared__ float tile[32][33];
    const float* in; unsigned short* out; int K, N, bx, by;
    if (bid < 3072)      { in=w_attn; out=wattnT; K=1024; N=3072; bx=bid%96;  by=bid/96; }
    else if (bid < 4096) { int lo=bid-3072; in=w_proj; out=wprojT; K=1024; N=1024; bx=lo%32;  by=lo/32; }
    else if (bid < 8192) { int lo=bid-4096; in=w_fc;   out=wfcT;   K=1024; N=4096; bx=lo%128; by=lo/128; }
    else                 { int lo=bid-8192; in=w_fc2;  out=wfc2T;  K=4096; N=1024; bx=lo%32;  by=lo/32; }
    int tx = t & 31, ty = t >> 5;
    int n0 = bx * 32, k0 = by * 32;
    #pragma unroll
    for (int i = 0; i < 4; i++)
        tile[ty + 8*i][tx] = in[(size_t)(k0 + ty + 8*i) * N + n0 + tx];
    __syncthreads();
    #pragma unroll
    for (int i = 0; i < 4; i++)
        out[(size_t)(n0 + ty + 8*i) * K + k0 + tx] = f2bf(tile[tx][ty + 8*i]);
}

// ---------------- layernorm (ln2): x f32 [.][1024] -> y bf16
__global__ __launch_bounds__(256)
void ln_kernel(const float* __restrict__ x, const float* __restrict__ g,
               const float* __restrict__ be, unsigned short* __restrict__ y){
    const int row = blockIdx.x, t = threadIdx.x;
    const float4* xr = (const float4*)(x + (size_t)row * TC);
    float4 v = xr[t];
    float s  = v.x + v.y + v.z + v.w;
    float s2 = v.x*v.x + v.y*v.y + v.z*v.z + v.w*v.w;
    #pragma unroll
    for (int off = 32; off; off >>= 1){
        s  += __shfl_down(s,  off);
        s2 += __shfl_down(s2, off);
    }
    __shared__ float red[8];
    int l = t & 63, wv = t >> 6;
    if (l == 0){ red[wv] = s; red[4 + wv] = s2; }
    __syncthreads();
    float S  = red[0] + red[1] + red[2] + red[3];
    float S2 = red[4] + red[5] + red[6] + red[7];
    float mu = S * (1.f / TC);
    float var = S2 * (1.f / TC) - mu * mu;
    float rs = rsqrtf(var + 1e-5f);
    int c = t * 4;
    float4 gg = *(const float4*)(g + c);
    float4 bb = *(const float4*)(be + c);
    u16x4 o;
    o[0] = f2bf((v.x - mu) * rs * gg.x + bb.x);
    o[1] = f2bf((v.y - mu) * rs * gg.y + bb.y);
    o[2] = f2bf((v.z - mu) * rs * gg.z + bb.z);
    o[3] = f2bf((v.w - mu) * rs * gg.w + bb.w);
    *(u16x4*)(y + (size_t)row * TC + c) = o;
}

// ---------------- 128x128 GEMM (m97 structure) + XCD swizzle
// EPI 0: +bias->bf16 ; 1: +bias+resid->f32 ; 2: +bias,gelu->bf16
template<int EPI>
__global__ __launch_bounds__(256, 2)
void gemm_bt(const unsigned short* __restrict__ A,
             const unsigned short* __restrict__ Bt,
             const float* __restrict__ bias,
             const float* __restrict__ resid,
             void* __restrict__ outv,
             int M, int N, int K){
    __shared__ unsigned short lA[128 * 32];
    __shared__ unsigned short lB[128 * 32];
    const int t = threadIdx.x, w = t >> 6, l = t & 63, lr = l & 15, lg = l >> 4;
    const int nt = N >> 7;
    const int nwg = gridDim.x;
    const int bid = blockIdx.x;
    int wg = (nwg & 7) ? bid : ((bid & 7) * (nwg >> 3) + (bid >> 3));
    const int bm = wg / nt, bn = wg % nt;
    const int row0 = bm << 7, col0 = bn << 7;
    const int wr = w >> 1, wc = w & 1;

    f32x4 acc[4][4];
    #pragma unroll
    for (int i = 0; i < 4; i++)
        #pragma unroll
        for (int j = 0; j < 4; j++) acc[i][j] = (f32x4){0.f,0.f,0.f,0.f};

    const char* Ag = (const char*)(A + (size_t)(row0 + (t >> 2)) * K) + (t & 3) * 16;
    const char* Bg = (const char*)(Bt + (size_t)(col0 + (t >> 2)) * K) + (t & 3) * 16;
    const size_t rstep = (size_t)64 * K * 2;
    char* lAw = (char*)lA + w * 1024;
    char* lBw = (char*)lB + w * 1024;

    for (int k0 = 0; k0 < K; k0 += 32){
        size_t kb = (size_t)k0 * 2;
        gl_lds16(Ag + kb,          lAw);
        gl_lds16(Ag + kb + rstep,  lAw + 4096);
        gl_lds16(Bg + kb,          lBw);
        gl_lds16(Bg + kb + rstep,  lBw + 4096);
        __syncthreads();
        bf16x8 af[4], bfr[4];
        #pragma unroll
        for (int mi = 0; mi < 4; mi++)
            af[mi] = ldbf8(lA + (wr*64 + mi*16 + lr) * 32 + lg * 8);
        #pragma unroll
        for (int ni = 0; ni < 4; ni++)
            bfr[ni] = ldbf8(lB + (wc*64 + ni*16 + lr) * 32 + lg * 8);
        #pragma unroll
        for (int mi = 0; mi < 4; mi++)
            #pragma unroll
            for (int ni = 0; ni < 4; ni++)
                acc[mi][ni] = __builtin_amdgcn_mfma_f32_16x16x32_bf16(
                    af[mi], bfr[ni], acc[mi][ni], 0, 0, 0);
        __syncthreads();
    }

    float bcol[4];
    #pragma unroll
    for (int ni = 0; ni < 4; ni++) bcol[ni] = bias[col0 + wc*64 + ni*16 + lr];
    #pragma unroll
    for (int mi = 0; mi < 4; mi++){
        #pragma unroll
        for (int j = 0; j < 4; j++){
            int row = row0 + wr*64 + mi*16 + lg*4 + j;
            size_t base = (size_t)row * N + col0 + wc*64 + lr;
            #pragma unroll
            for (int ni = 0; ni < 4; ni++){
                float v = acc[mi][ni][j] + bcol[ni];
                size_t idx = base + (size_t)ni * 16;
                if (EPI == 0)      ((unsigned short*)outv)[idx] =
                    __builtin_bit_cast(unsigned short, (__bf16)v);
                else if (EPI == 1) ((float*)outv)[idx] = v + resid[idx];
                else               ((unsigned short*)outv)[idx] =
                    __builtin_bit_cast(unsigned short, (__bf16)gelu_tanh(v));
            }
        }
    }
}

// ---------------- 256x256 GEMM pieces
template<int MH>
__device__ __forceinline__ void gloadA(const unsigned short* bufA, bf16x8 (&af)[4][2],
                                       int wm, int lr, int sl0, int sl1){
    #pragma unroll
    for (int i = 0; i < 4; i++){
        int lrow = (wm*128 + (MH*4 + i)*16 + lr) * 64;
        af[i][0] = ldbf8(bufA + lrow + sl0);
        af[i][1] = ldbf8(bufA + lrow + sl1);
    }
}
__device__ __forceinline__ void gloadB(const unsigned short* bufB, bf16x8 (&bfr)[4][2],
                                       int wn, int lr, int sl0, int sl1){
    #pragma unroll
    for (int i = 0; i < 4; i++){
        int brow = (wn*64 + i*16 + lr) * 64;
        bfr[i][0] = ldbf8(bufB + brow + sl0);
        bfr[i][1] = ldbf8(bufB + brow + sl1);
    }
}
template<int MH, int NH>
__device__ __forceinline__ void gmma(const bf16x8 (&af)[4][2], const bf16x8 (&bfr)[4][2],
                                     f32x4 (&acc)[8][4]){
    #pragma unroll
    for (int i = 0; i < 4; i++)
        #pragma unroll
        for (int j = 0; j < 2; j++){
            f32x4& a = acc[MH*4 + i][NH*2 + j];
            a = __builtin_amdgcn_mfma_f32_16x16x32_bf16(af[i][0], bfr[NH*2+j][0], a, 0,0,0);
            a = __builtin_amdgcn_mfma_f32_16x16x32_bf16(af[i][1], bfr[NH*2+j][1], a, 0,0,0);
        }
}

// 256x256 K-loop: 2 barriers/tile, reads+MFMA free-scheduled (compiler lgkmcnt),
// double-buffered with counted vmcnt(2).
#define G256_LOOP(NT_, KBEG_)                                                   \
    for (int tk = 0; tk < (NT_); ++tk){                                         \
        const int cur = tk & 1;                                                 \
        const bool more1 = (tk + 1) < (NT_);                                    \
        const bool more2 = (tk + 2) < (NT_);                                    \
        const unsigned short* bufA = &lds[cur][0][0];                           \
        const unsigned short* bufB = &lds[cur][1][0];                           \
        if (more1) asm volatile("s_waitcnt vmcnt(2)" ::: "memory");             \
        else       asm volatile("s_waitcnt vmcnt(0)" ::: "memory");             \
        __builtin_amdgcn_s_barrier();                                           \
        {                                                                       \
            bf16x8 afr[4][2], bfr[4][2];                                        \
            gloadA<0>(bufA, afr, wm, lr, sl0, sl1);                             \
            gloadB(bufB, bfr, wn, lr, sl0, sl1);                                \
            if (more1){                                                         \
                stage(cur ^ 1, (KBEG_) + (tk + 1)*64, 1);                       \
                stage(cur ^ 1, (KBEG_) + (tk + 1)*64, 2);                       \
            }                                                                   \
            __builtin_amdgcn_s_setprio(1);                                      \
            gmma<0,0>(afr, bfr, acc);                                           \
            gmma<0,1>(afr, bfr, acc);                                           \
            __builtin_amdgcn_s_setprio(0);                                      \
            gloadA<1>(bufA, afr, wm, lr, sl0, sl1);                             \
            if (more1) stage(cur ^ 1, (KBEG_) + (tk + 1)*64, 3);                \
            __builtin_amdgcn_s_setprio(1);                                      \
            gmma<1,0>(afr, bfr, acc);                                           \
            gmma<1,1>(afr, bfr, acc);                                           \
            __builtin_amdgcn_s_setprio(0);                                      \
        }                                                                       \
        __builtin_amdgcn_s_barrier();                                           \
        if (more2) stage(cur, (KBEG_) + (tk + 2)*64, 0);                        \
    }

template<int EPI>  // 0: +bias->bf16 ; 2: +bias,gelu->bf16
__global__ __launch_bounds__(512, 1)
void gemm256(const unsigned short* __restrict__ A,
             const unsigned short* __restrict__ Bt,
             const float* __restrict__ bias,
             void* __restrict__ outv,
             int M, int N, int K){
    __shared__ unsigned short lds[2][2][256*64];
    const int t = threadIdx.x;
    const int w = t >> 6, l = t & 63, lr = l & 15, lg = l >> 4;
    const int wm = w >> 2, wn = w & 3;
    const int lr7 = lr & 7;
    const int sl0 = (lg ^ lr7) << 3;
    const int sl1 = ((4 + lg) ^ lr7) << 3;
    const int nbn = N >> 8;
    const int nwg = (M >> 8) * nbn;
    const int bid = blockIdx.x;
    const int wg = (nwg & 7) ? bid : ((bid & 7) * (nwg >> 3) + (bid >> 3));
    const int bm = wg / nbn, bn = wg % nbn;
    const size_t row0 = (size_t)bm << 8, col0 = (size_t)bn << 8;
    const int NT = K >> 6;

    f32x4 acc[8][4];
    #pragma unroll
    for (int i = 0; i < 8; i++)
        #pragma unroll
        for (int j = 0; j < 4; j++) acc[i][j] = (f32x4){0.f,0.f,0.f,0.f};

    int rowc[4], slogc[4];
    #pragma unroll
    for (int c = 0; c < 4; c++){
        int seg = t + (c << 9);
        rowc[c]  = seg >> 3;
        slogc[c] = (((seg & 7) ^ ((seg >> 3) & 7)) << 3);
    }
    const unsigned short* Abase = A  + row0 * K;
    const unsigned short* Bbase = Bt + col0 * K;
    auto stage = [&](int buf, int kofs, int c){
        int seg = t + (c << 9);
        const unsigned short* sa = Abase + (size_t)rowc[c] * K + kofs + slogc[c];
        const unsigned short* sb = Bbase + (size_t)rowc[c] * K + kofs + slogc[c];
        gl_lds16(sa, (void*)&lds[buf][0][seg * 8]);
        gl_lds16(sb, (void*)&lds[buf][1][seg * 8]);
    };

    #pragma unroll
    for (int c = 0; c < 4; c++) stage(0, 0, c);
    if (NT > 1) stage(1, 64, 0);

    G256_LOOP(NT, 0)

    float bcol[4];
    #pragma unroll
    for (int ni = 0; ni < 4; ni++) bcol[ni] = bias[col0 + wn*64 + ni*16 + lr];
    unsigned short* outp = (unsigned short*)outv;
    #pragma unroll
    for (int mi = 0; mi < 8; mi++){
        #pragma unroll
        for (int j = 0; j < 4; j++){
            size_t row = row0 + wm*128 + mi*16 + lg*4 + j;
            size_t base = row * N + col0 + wn*64 + lr;
            #pragma unroll
            for (int ni = 0; ni < 4; ni++){
                float v = acc[mi][ni][j] + bcol[ni];
                size_t idx = base + (size_t)ni * 16;
                if (EPI == 0) outp[idx] = __builtin_bit_cast(unsigned short, (__bf16)v);
                else          outp[idx] = __builtin_bit_cast(unsigned short, (__bf16)gelu_tanh(v));
            }
        }
    }
}

// ---------------- 256x256 split-K GEMM: grid = SK*(M/256)*(N/256); bf16 partials
__global__ __launch_bounds__(512, 1)
void gemm256sk(const unsigned short* __restrict__ A,
               const unsigned short* __restrict__ Bt,
               unsigned short* __restrict__ pout,
               int M, int N, int K, int klen){
    __shared__ unsigned short lds[2][2][256*64];
    const int t = threadIdx.x;
    const int w = t >> 6, l = t & 63, lr = l & 15, lg = l >> 4;
    const int wm = w >> 2, wn = w & 3;
    const int lr7 = lr & 7;
    const int sl0 = (lg ^ lr7) << 3;
    const int sl1 = ((4 + lg) ^ lr7) << 3;
    const int nbn = N >> 8;
    const int ntile = (M >> 8) * nbn;
    const int nwg = gridDim.x;
    const int bid = blockIdx.x;
    int wg = (nwg & 7) ? bid : ((bid & 7) * (nwg >> 3) + (bid >> 3));
    const int kh = wg / ntile;
    wg -= kh * ntile;
    const int bm = wg / nbn, bn = wg % nbn;
    const size_t row0 = (size_t)bm << 8, col0 = (size_t)bn << 8;
    const int NT = klen >> 6;
    const int kbeg = kh * klen;

    f32x4 acc[8][4];
    #pragma unroll
    for (int i = 0; i < 8; i++)
        #pragma unroll
        for (int j = 0; j < 4; j++) acc[i][j] = (f32x4){0.f,0.f,0.f,0.f};

    int rowc[4], slogc[4];
    #pragma unroll
    for (int c = 0; c < 4; c++){
        int seg = t + (c << 9);
        rowc[c]  = seg >> 3;
        slogc[c] = (((seg & 7) ^ ((seg >> 3) & 7)) << 3);
    }
    const unsigned short* Abase = A  + row0 * K;
    const unsigned short* Bbase = Bt + col0 * K;
    auto stage = [&](int buf, int kofs, int c){
        int seg = t + (c << 9);
        const unsigned short* sa = Abase + (size_t)rowc[c] * K + kofs + slogc[c];
        const unsigned short* sb = Bbase + (size_t)rowc[c] * K + kofs + slogc[c];
        gl_lds16(sa, (void*)&lds[buf][0][seg * 8]);
        gl_lds16(sb, (void*)&lds[buf][1][seg * 8]);
    };

    #pragma unroll
    for (int c = 0; c < 4; c++) stage(0, kbeg, c);
    if (NT > 1) stage(1, kbeg + 64, 0);

    G256_LOOP(NT, kbeg)

    unsigned short* outp = pout + (size_t)kh * M * N;
    #pragma unroll
    for (int mi = 0; mi < 8; mi++){
        #pragma unroll
        for (int j = 0; j < 4; j++){
            size_t row = row0 + wm*128 + mi*16 + lg*4 + j;
            size_t base = row * N + col0 + wn*64 + lr;
            #pragma unroll
            for (int ni = 0; ni < 4; ni++)
                outp[base + (size_t)ni * 16] =
                    __builtin_bit_cast(unsigned short, (__bf16)acc[mi][ni][j]);
        }
    }
}

// ---------------- split-K x4 combine: out = sum(p[0..3]) + bias + resid (f32)
__global__ __launch_bounds__(256)
void combine_k4(const unsigned short* __restrict__ p,
                const float* __restrict__ bias, const float* __restrict__ resid,
                float* __restrict__ out){
    const size_t PS = (size_t)TM * TC;
    const int total = TM * TC / 4;
    for (int i = blockIdx.x * 256 + threadIdx.x; i < total; i += gridDim.x * 256){
        int e = i * 4;
        u16x4 a0 = *(const u16x4*)(p + e);
        u16x4 a1 = *(const u16x4*)(p + PS + e);
        u16x4 a2 = *(const u16x4*)(p + 2*PS + e);
        u16x4 a3 = *(const u16x4*)(p + 3*PS + e);
        float4 r = *(const float4*)(resid + e);
        float4 bb = *(const float4*)(bias + (e & (TC - 1)));
        float4 o;
        o.x = bf2f(a0[0]) + bf2f(a1[0]) + bf2f(a2[0]) + bf2f(a3[0]) + r.x + bb.x;
        o.y = bf2f(a0[1]) + bf2f(a1[1]) + bf2f(a2[1]) + bf2f(a3[1]) + r.y + bb.y;
        o.z = bf2f(a0[2]) + bf2f(a1[2]) + bf2f(a2[2]) + bf2f(a3[2]) + r.z + bb.z;
        o.w = bf2f(a0[3]) + bf2f(a1[3]) + bf2f(a2[3]) + bf2f(a3[3]) + r.w + bb.w;
        *(float4*)(out + e) = o;
    }
}

// ---------------- V pre-transpose: qkv [tok][3C] -> vTg [bh][kt][64 d][80]
__global__ __launch_bounds__(256)
void vtrans(const unsigned short* __restrict__ qkv, unsigned short* __restrict__ vTg){
    __shared__ unsigned short lt[64][68];
    int kt = blockIdx.x & (NQT - 1);
    int bh = blockIdx.x >> 5;
    int h = bh & (TH - 1), b = bh >> 4;
    int t = threadIdx.x;
    int r = t >> 2, c4 = t & 3;
    const unsigned short* src = qkv + (size_t)(b*TT + kt*64 + r) * (3*TC) + 2*TC + h*THD;
    u16x8 a0 = *(const u16x8*)(src + c4*8);
    u16x8 a1 = *(const u16x8*)(src + 32 + c4*8);
    #pragma unroll
    for (int j = 0; j < 8; j++){
        lt[r][c4*8 + j]      = a0[j];
        lt[r][32 + c4*8 + j] = a1[j];
    }
    __syncthreads();
    int d = t >> 2;
    unsigned short* dst = vTg + ((size_t)bh * NQT + kt) * (64*80) + (size_t)d * 80;
    u16x8 o0, o1;
    #pragma unroll
    for (int j = 0; j < 8; j++){
        o0[j] = lt[c4*8 + j][d];
        o1[j] = lt[32 + c4*8 + j][d];
    }
    *(u16x8*)(dst + c4*8)      = o0;
    *(u16x8*)(dst + 32 + c4*8) = o1;
}

// ---------------- flash attention (causal): 1024 blocks (bh x 32 q-tiles of 64 rows),
// 4 waves x 16 q-rows; KVBLK=128; SWAPPED QK^T (mfma(K,Q) -> S^T);
// split-operand pipeline: K staged under PV+loop, V staged under QK+softmax.
__global__ __launch_bounds__(256, 3)
void attn_kernel(const unsigned short* __restrict__ qkv,
                 const unsigned short* __restrict__ vTg,
                 unsigned short* __restrict__ attn_out){
    __shared__ unsigned short kbuf[128*64];   // 16 KB (2 kv tiles)
    __shared__ unsigned short vbuf[128*64];   // 16 KB (2 V^T tiles)
    __shared__ unsigned short pl[4][16*136];  // 17.4 KB  (total ~49.4 KB -> 3/CU)

    const int bid = blockIdx.x;
    const int qrank = bid >> 5;          // 0..31, 0 = longest
    const int bh = bid & 31;
    const int h = bh & (TH - 1), b = bh >> 4;
    const int qb = 31 - qrank;           // q-tile (64 rows)
    const int q0 = qb << 6;
    const int t = threadIdx.x, w = t >> 6, l = t & 63, lr = l & 15, lg = l >> 4;
    const int lr7 = lr & 7;
    const int sl0 = (lg ^ lr7) << 3;
    const int sl1 = ((4 + lg) ^ lr7) << 3;
    const float SC = 0.18033688011112042f;   // 0.125 * log2(e)

    const int NP = (qb >> 1) + 1;            // kv pairs
    const int qrow_base = q0 + w*16;
    const int myq = qrow_base + lr;          // this thread's q-row (softmax state owner)

    // staging: 4 virtual 256-thread passes per operand; dest = vt*16B (lane-contig)
    const unsigned short* kgp[4];
    const unsigned short* vgp[4];
    #pragma unroll
    for (int p = 0; p < 4; p++){
        int vt = p*256 + t;
        int r  = vt >> 3;
        int sc = ((vt & 7) ^ (r & 7)) * 8;
        kgp[p] = qkv + (size_t)(b*TT + r) * (3*TC) + TC + h*THD + sc;
        vgp[p] = vTg + (size_t)bh * (NQT*64*80)
               + (size_t)(r >> 6) * (64*80) + (size_t)(r & 63) * 80 + sc;
    }
    const size_t kstep2 = (size_t)128 * (3*TC);   // 2 token-tiles
    const size_t vstep2 = (size_t)2 * (64*80);

    auto stage_k = [&](int pi){
        #pragma unroll
        for (int p = 0; p < 4; p++)
            gl_lds16(kgp[p] + (size_t)pi*kstep2, (void*)&kbuf[(p*256 + t)*8]);
    };
    auto stage_v = [&](int pi){
        #pragma unroll
        for (int p = 0; p < 4; p++)
            gl_lds16(vgp[p] + (size_t)pi*vstep2, (void*)&vbuf[(p*256 + t)*8]);
    };

    const unsigned short* qr =
        qkv + (size_t)(b*TT + myq) * (3*TC) + h*THD;
    bf16x8 q0f = ldbf8(qr + lg*8), q1f = ldbf8(qr + 32 + lg*8);

    bf16x8 ones;
    #pragma unroll
    for (int i = 0; i < 8; i++) ones[i] = (__bf16)1.0f;

    f32x4 o[5];
    float m = -1e30f;   // running max (scaled/log2 domain) for q-row `myq`
    #pragma unroll
    for (int i = 0; i < 5; i++) o[i] = (f32x4){0.f,0.f,0.f,0.f};

    unsigned short* plw = &pl[w][0];

    stage_k(0);
    for (int pi = 0; pi < NP; ++pi){
        const int t0 = 2*pi, t1 = 2*pi + 1;
        // K[pi] ready (issued last iteration under PV); barrier also certifies
        // all waves finished reading vbuf[pi-1] -> safe to issue V[pi].
        asm volatile("s_waitcnt vmcnt(0)" ::: "memory");
        __builtin_amdgcn_s_barrier();
        stage_v(pi);

        // ---- S^T = K Q^T over 128 kv: s[cb][j] = S[kv = cb*16+lg*4+j][q = lr] ----
        f32x4 s[8];
        __builtin_amdgcn_s_setprio(1);
        #pragma unroll
        for (int cb = 0; cb < 8; cb++){
            bf16x8 ka = ldbf8(kbuf + (cb*16 + lr)*64 + sl0);
            bf16x8 kbf = ldbf8(kbuf + (cb*16 + lr)*64 + sl1);
            f32x4 z = (f32x4){0.f,0.f,0.f,0.f};
            z = __builtin_amdgcn_mfma_f32_16x16x32_bf16(ka, q0f, z, 0,0,0);
            z = __builtin_amdgcn_mfma_f32_16x16x32_bf16(kbf, q1f, z, 0,0,0);
            s[cb] = z;
        }
        __builtin_amdgcn_s_setprio(0);
        // ---- causal masks: kv_global = tile*64 + cb*16 + lg*4 + j vs q = myq ----
        if (t0 == qb){
            #pragma unroll
            for (int cb = 0; cb < 4; cb++)
                #pragma unroll
                for (int j = 0; j < 4; j++)
                    if (t0*64 + cb*16 + lg*4 + j > myq) s[cb][j] = -1e30f;
        }
        if (t1 == qb){
            #pragma unroll
            for (int cb = 4; cb < 8; cb++)
                #pragma unroll
                for (int j = 0; j < 4; j++)
                    if (t1*64 + (cb-4)*16 + lg*4 + j > myq) s[cb][j] = -1e30f;
        } else if (t1 > qb){
            #pragma unroll
            for (int cb = 4; cb < 8; cb++)
                #pragma unroll
                for (int j = 0; j < 4; j++) s[cb][j] = -1e30f;
        }
        // ---- row max: local 32-chain + 2-step cross-lane (lanes sharing lr) ----
        float mloc = s[0][0];
        #pragma unroll
        for (int cb = 0; cb < 8; cb++)
            #pragma unroll
            for (int j = 0; j < 4; j++) mloc = fmaxf(mloc, s[cb][j]);
        mloc = fmaxf(mloc, __shfl_xor(mloc, 16));
        mloc = fmaxf(mloc, __shfl_xor(mloc, 32));
        // ---- defer-max rescale (exact skip) ----
        bool grow = (mloc * SC > m);
        float al = 1.f;
        if (__any(grow)){
            float mn = fmaxf(m, mloc * SC);
            al = exp2f(m - mn);
            m = mn;
            float alb[4];
            #pragma unroll
            for (int j = 0; j < 4; j++) alb[j] = __shfl(al, lg*4 + j);
            #pragma unroll
            for (int db = 0; db < 5; db++)
                #pragma unroll
                for (int j = 0; j < 4; j++) o[db][j] *= alb[j];
        }
        // ---- P = exp2(s*SC - m), native bf16 casts, packed b64 writes ----
        #pragma unroll
        for (int cb = 0; cb < 8; cb++){
            u16x4 pk;
            #pragma unroll
            for (int j = 0; j < 4; j++){
                float e = exp2f(__builtin_fmaf(s[cb][j], SC, -m));
                pk[j] = __builtin_bit_cast(unsigned short, (__bf16)e);
            }
            *(u16x4*)(plw + lr*136 + cb*16 + lg*4) = pk;
        }
        // ---- V[pi] ready; barrier certifies all waves done reading kbuf[pi] ----
        asm volatile("s_waitcnt vmcnt(0)" ::: "memory");
        __builtin_amdgcn_s_barrier();
        if (pi + 1 < NP) stage_k(pi + 1);   // kbuf overwrite safe; hides under PV

        // ---- PV over both kv tiles ----
        bf16x8 pa0 = ldbf8(plw + lr*136 + lg*8);
        bf16x8 pa1 = ldbf8(plw + lr*136 + 32 + lg*8);
        bf16x8 pa2 = ldbf8(plw + lr*136 + 64 + lg*8);
        bf16x8 pa3 = ldbf8(plw + lr*136 + 96 + lg*8);
        __builtin_amdgcn_s_setprio(1);
        #pragma unroll
        for (int db = 0; db < 4; db++){
            bf16x8 v0a = ldbf8(vbuf + (db*16 + lr)*64 + sl0);
            bf16x8 v0b = ldbf8(vbuf + (db*16 + lr)*64 + sl1);
            o[db] = __builtin_amdgcn_mfma_f32_16x16x32_bf16(pa0, v0a, o[db], 0,0,0);
            o[db] = __builtin_amdgcn_mfma_f32_16x16x32_bf16(pa1, v0b, o[db], 0,0,0);
            bf16x8 v1a = ldbf8(vbuf + (64 + db*16 + lr)*64 + sl0);
            bf16x8 v1b = ldbf8(vbuf + (64 + db*16 + lr)*64 + sl1);
            o[db] = __builtin_amdgcn_mfma_f32_16x16x32_bf16(pa2, v1a, o[db], 0,0,0);
            o[db] = __builtin_amdgcn_mfma_f32_16x16x32_bf16(pa3, v1b, o[db], 0,0,0);
        }
        o[4] = __builtin_amdgcn_mfma_f32_16x16x32_bf16(pa0, ones, o[4], 0,0,0);
        o[4] = __builtin_amdgcn_mfma_f32_16x16x32_bf16(pa1, ones, o[4], 0,0,0);
        o[4] = __builtin_amdgcn_mfma_f32_16x16x32_bf16(pa2, ones, o[4], 0,0,0);
        o[4] = __builtin_amdgcn_mfma_f32_16x16x32_bf16(pa3, ones, o[4], 0,0,0);
        __builtin_amdgcn_s_setprio(0);
    }

    __bf16* aout = (__bf16*)attn_out;
    #pragma unroll
    for (int j = 0; j < 4; j++){
        float inv = 1.f / o[4][j];
        size_t tok = (size_t)(b*TT + qrow_base + lg*4 + j);
        #pragma unroll
        for (int db = 0; db < 4; db++)
            aout[tok*TC + h*THD + db*16 + lr] = (__bf16)(o[db][j] * inv);
    }
}

extern "C" void kernel_launch(void* const* d_in, const int* in_sizes, int n_in,
                              void* d_out, int out_size, void* d_ws, size_t ws_size,
                              hipStream_t stream){
    const float* x      = (const float*)d_in[0];
    const float* ln1_g  = (const float*)d_in[1];
    const float* ln1_b  = (const float*)d_in[2];
    const float* w_attn = (const float*)d_in[3];
    const float* b_attn = (const float*)d_in[4];
    const float* w_proj = (const float*)d_in[5];
    const float* b_proj = (const float*)d_in[6];
    const float* ln2_g  = (const float*)d_in[7];
    const float* ln2_b  = (const float*)d_in[8];
    const float* w_fc   = (const float*)d_in[9];
    const float* b_fc   = (const float*)d_in[10];
    const float* w_fc2  = (const float*)d_in[11];
    const float* b_fc2  = (const float*)d_in[12];
    float* out = (float*)d_out;

    char* ws = (char*)d_ws;
    size_t off = 0;
    auto alloc = [&](size_t bytes) -> void* {
        void* p = ws + off;
        off += (bytes + 255) & ~(size_t)255;
        return p;
    };
    unsigned short* wattnT = (unsigned short*)alloc((size_t)3072*1024*2);
    unsigned short* wprojT = (unsigned short*)alloc((size_t)1024*1024*2);
    unsigned short* wfcT   = (unsigned short*)alloc((size_t)4096*1024*2);
    unsigned short* wfc2T  = (unsigned short*)alloc((size_t)1024*4096*2);
    unsigned short* xn1    = (unsigned short*)alloc((size_t)TM*TC*2);    // + qkvb = split-K partial arena
    unsigned short* qkvb   = (unsigned short*)alloc((size_t)TM*3*TC*2);
    float*          resid1 = (float*)alloc((size_t)TM*TC*4);
    unsigned short* xn2    = (unsigned short*)alloc((size_t)TM*TC*2);
    unsigned short* hbuf   = (unsigned short*)alloc((size_t)TM*4*TC*2);
    unsigned short* attnO  = (unsigned short*)alloc((size_t)TM*TC*2);
    unsigned short* vTg    = (unsigned short*)alloc((size_t)TB*TH*NQT*64*80*2);

    unsigned short* pks = xn1;   // 4 x TM*TC bf16 = exactly xn1+qkvb (dead after attn)

    prep_all<<<12288 + TM, 256, 0, stream>>>(
        w_attn, w_proj, w_fc, w_fc2, wattnT, wprojT, wfcT, wfc2T,
        x, ln1_g, ln1_b, xn1);

    gemm256<0><<<(TM/256)*(3072/256), 512, 0, stream>>>(
        xn1, wattnT, b_attn, qkvb, TM, 3072, 1024);

    vtrans<<<TB*TH*NQT, 256, 0, stream>>>(qkvb, vTg);

    attn_kernel<<<TB*TH*NQT, 256, 0, stream>>>(qkvb, vTg, attnO);

    gemm_bt<1><<<(TM/128)*(1024/128), 256, 0, stream>>>(
        attnO, wprojT, b_proj, x, resid1, TM, 1024, 1024);

    ln_kernel<<<TM, 256, 0, stream>>>(resid1, ln2_g, ln2_b, xn2);

    gemm256<2><<<(TM/256)*(4096/256), 512, 0, stream>>>(
        xn2, wfcT, b_fc, hbuf, TM, 4096, 1024);

    // FC2: 256x256 split-K x4 (256 blocks = 1/CU), bf16 partials, then combine
    gemm256sk<<<4*(TM/256)*(1024/256), 512, 0, stream>>>(
        hbuf, wfc2T, pks, TM, 1024, 4096, 1024);
    combine_k4<<<2048, 256, 0, stream>>>(pks, b_fc2, resid1, out);
}